// Round 3
// baseline (792.051 us; speedup 1.0000x reference)
//
#include <hip/hip_runtime.h>
#include <hip/hip_bf16.h>
#include <math.h>

typedef unsigned short u16;
typedef __attribute__((ext_vector_type(8))) short bf16x8;
typedef __attribute__((ext_vector_type(4))) float f32x4;

#define MFMA_BF16 __builtin_amdgcn_mfma_f32_16x16x32_bf16

__device__ __forceinline__ u16 f2bf(float f){
  union { float f; unsigned u; } v; v.f = f;
  unsigned r = v.u + 0x7FFFu + ((v.u >> 16) & 1u);
  return (u16)(r >> 16);
}

__device__ __forceinline__ void gll16(const void* g, void* l){
  __builtin_amdgcn_global_load_lds(
      (const __attribute__((address_space(1))) unsigned int*)g,
      (__attribute__((address_space(3))) unsigned int*)l, 16, 0, 0);
}

// ---------------- weight prep: fp32 [K][N] -> bf16 [N][K] ----------------
__global__ void k_transpose(const float* __restrict__ src, u16* __restrict__ dst, int K, int N){
  int idx = blockIdx.x*256 + threadIdx.x;
  if (idx >= K*N) return;
  int n = idx / K, k = idx - n*K;
  dst[idx] = f2bf(src[(size_t)k*N + n]);
}

__global__ void k_concat_bias(const float* __restrict__ a, const float* __restrict__ b,
                              const float* __restrict__ c, float* __restrict__ o){
  int i = threadIdx.x;  // 768 threads
  o[i] = i < 256 ? a[i] : (i < 512 ? b[i-256] : c[i-512]);
}

// ---- fused rel-pos bias + shift mask table: fb[cls][head][m][n] ----
__global__ __launch_bounds__(256) void k_bias(const float* __restrict__ btab, float* __restrict__ fb){
  int idx = blockIdx.x*256 + threadIdx.x;   // 4*8*64*64 = 131072
  int n = idx & 63, m = (idx >> 6) & 63, hh = (idx >> 12) & 7, cls = idx >> 15;
  int r1=m>>3, c1=m&7, r2=n>>3, c2=n&7;
  float bv = btab[((r1-r2+7)*15 + (c1-c2+7))*8 + hh];
  int whe = cls>>1, wwe = cls&1;
  int a1 = (whe ? (r1<4?1:2) : 0)*3 + (wwe ? (c1<4?1:2) : 0);
  int a2 = (whe ? (r2<4?1:2) : 0)*3 + (wwe ? (c2<4?1:2) : 0);
  fb[idx] = bv + ((a1!=a2) ? -100.f : 0.f);
}

// ------------- LN1 + cyclic shift + window partition -> bf16 -------------
__global__ __launch_bounds__(256) void k_ln1(const float* __restrict__ x, const float* __restrict__ g,
                                             const float* __restrict__ b, u16* __restrict__ out){
  int lane = threadIdx.x & 63;
  int m = blockIdx.x*4 + (threadIdx.x >> 6);
  int bi = m >> 12, win = (m >> 6) & 63, p = m & 63;
  int h = ((win >> 3)*8 + (p >> 3) + 4) & 63;
  int w = ((win & 7)*8 + (p & 7) + 4) & 63;
  float4 v = ((const float4*)(x + ((size_t)bi*4096 + h*64 + w)*256))[lane];
  float s = v.x+v.y+v.z+v.w, sq = v.x*v.x+v.y*v.y+v.z*v.z+v.w*v.w;
  for (int off=32; off; off>>=1){ s += __shfl_xor(s, off); sq += __shfl_xor(sq, off); }
  float mean = s*(1.f/256.f);
  float inv = rsqrtf(sq*(1.f/256.f) - mean*mean + 1e-5f);
  float4 gg = ((const float4*)g)[lane], bb = ((const float4*)b)[lane];
  ushort4 o;
  o.x = f2bf((v.x-mean)*inv*gg.x + bb.x);
  o.y = f2bf((v.y-mean)*inv*gg.y + bb.y);
  o.z = f2bf((v.z-mean)*inv*gg.z + bb.z);
  o.w = f2bf((v.w-mean)*inv*gg.w + bb.w);
  ((ushort4*)(out + (size_t)m*256))[lane] = o;
}

// ---------------- GEMM: A[M][K] bf16 @ Bt[N][K] bf16, fp32 acc ----------------
// BM=BN=128, BK=64, 4 waves (2x2, 64x64 each), global_load_lds, XCD swizzle.
// EPI 0: +bias(qkv concat), q scaled, scatter q/k [wh][tok][dim], v TRANSPOSED [wh][dim][tok]
// EPI 2: +b1, exact GELU, bf16 row-major out
// EPI 3: +b2, +hs residual, fp32 out
template<int EPI>
__global__ __launch_bounds__(256) void k_gemm(const u16* __restrict__ A, const u16* __restrict__ Bt,
                                              const float* __restrict__ bias, const float* __restrict__ res,
                                              void* __restrict__ outp, int K){
  __shared__ __align__(16) u16 As[128*64];
  __shared__ __align__(16) u16 Bs[128*64];
  int tid = threadIdx.x, lane = tid & 63, wid = tid >> 6;
  int g = lane >> 4, lr = lane & 15;
  int wr = wid >> 1, wc = wid & 1;
  // bijective XCD-chunked swizzle (nwg % 8 == 0 for all our grids)
  int nwg = gridDim.x*gridDim.y;
  int bid = blockIdx.y*gridDim.x + blockIdx.x;
  int cpx = nwg >> 3;
  int swz = (bid & 7)*cpx + (bid >> 3);
  int bx = swz % gridDim.x, by = swz / gridDim.x;
  int m0 = by*128, n0 = bx*128;
  const u16* Aw = A + (size_t)m0*K;
  const u16* Bw = Bt + (size_t)n0*K;
  int srow = (lane >> 3);
  int scol = (lane & 7)*8;
  f32x4 acc[4][4] = {};
  for (int k0 = 0; k0 < K; k0 += 64){
    __syncthreads();
#pragma unroll
    for (int c = 0; c < 4; c++){
      int chunk = wid*4 + c;
      int row = chunk*8 + srow;
      gll16(Aw + (size_t)row*K + k0 + scol, As + chunk*512);
      gll16(Bw + (size_t)row*K + k0 + scol, Bs + chunk*512);
    }
    __syncthreads();
#pragma unroll
    for (int kk = 0; kk < 2; kk++){
      bf16x8 af[4], bf[4];
#pragma unroll
      for (int i=0;i<4;i++){
        af[i] = *(const bf16x8*)(As + (wr*64 + i*16 + lr)*64 + kk*32 + 8*g);
        bf[i] = *(const bf16x8*)(Bs + (wc*64 + i*16 + lr)*64 + kk*32 + 8*g);
      }
#pragma unroll
      for (int mi=0;mi<4;mi++)
#pragma unroll
      for (int nj=0;nj<4;nj++)
        acc[mi][nj] = MFMA_BF16(af[mi], bf[nj], acc[mi][nj], 0,0,0);
    }
  }
  const float scale = 0.1767766952966369f; // 32^-0.5
#pragma unroll
  for (int mi=0; mi<4; mi++)
#pragma unroll
  for (int nj=0; nj<4; nj++){
    int n = n0 + wc*64 + nj*16 + lr;
    if constexpr (EPI==0){
      int sec = n >> 8, ch = n & 255, head = ch >> 5, dim = ch & 31;
      if (sec < 2){
#pragma unroll
        for (int r=0; r<4; r++){
          int m = m0 + wr*64 + mi*16 + 4*g + r;
          float val = acc[mi][nj][r] + bias[n];
          if (sec == 0) val *= scale;
          size_t off = (size_t)sec*33554432u
                     + (((size_t)((m >> 6)*8 + head))*64 + (m & 63))*32 + dim;
          ((u16*)outp)[off] = f2bf(val);
        }
      } else {
        ushort4 pack;
        float bv = bias[n];
        pack.x = f2bf(acc[mi][nj][0] + bv);
        pack.y = f2bf(acc[mi][nj][1] + bv);
        pack.z = f2bf(acc[mi][nj][2] + bv);
        pack.w = f2bf(acc[mi][nj][3] + bv);
        int m_ = m0 + wr*64 + mi*16 + 4*g;
        size_t off = (size_t)2*33554432u
                   + (((size_t)((m_ >> 6)*8 + head))*32 + dim)*64 + (m_ & 63);
        *(ushort4*)((u16*)outp + off) = pack;
      }
    } else {
#pragma unroll
      for (int r=0; r<4; r++){
        int m = m0 + wr*64 + mi*16 + 4*g + r;
        float val = acc[mi][nj][r] + bias[n];
        if constexpr (EPI==2){
          float gv = 0.5f*val*(1.f + erff(val*0.70710678118654752f));
          ((u16*)outp)[(size_t)m*1024 + n] = f2bf(gv);
        } else {
          ((float*)outp)[(size_t)m*256 + n] = val + res[(size_t)m*256 + n];
        }
      }
    }
  }
}

// ------- O-proj (BN=256 full row) + window reverse + residual + fused LN2 -------
// A[M][256] bf16 @ woT[256][256] bf16. Writes hs (fp32, token order, d_out)
// and y2 = LN2(hs) (bf16, token order).
__global__ __launch_bounds__(256) void k_oproj(const u16* __restrict__ A, const u16* __restrict__ Bt,
                                               const float* __restrict__ bo, const float* __restrict__ hidden,
                                               const float* __restrict__ g2, const float* __restrict__ b2v,
                                               float* __restrict__ hs_out, u16* __restrict__ y2){
  __shared__ __align__(16) u16 As[128*64];
  __shared__ __align__(16) u16 Bs[256*64];
  __shared__ float part_s[128][2];
  __shared__ float part_q[128][2];
  int tid = threadIdx.x, lane = tid & 63, wid = tid >> 6;
  int g = lane >> 4, lr = lane & 15;
  int wr = wid >> 1, wc = wid & 1;
  int m0 = blockIdx.x*128;
  const u16* Aw = A + (size_t)m0*256;
  int srow = (lane >> 3);
  int scol = (lane & 7)*8;
  f32x4 acc[4][8] = {};
  for (int k0 = 0; k0 < 256; k0 += 64){
    __syncthreads();
#pragma unroll
    for (int c = 0; c < 4; c++){
      int chunk = wid*4 + c;
      int row = chunk*8 + srow;
      gll16(Aw + (size_t)row*256 + k0 + scol, As + chunk*512);
    }
#pragma unroll
    for (int c = 0; c < 8; c++){
      int chunk = wid*8 + c;
      int row = chunk*8 + srow;
      gll16(Bt + (size_t)row*256 + k0 + scol, Bs + chunk*512);
    }
    __syncthreads();
#pragma unroll
    for (int kk = 0; kk < 2; kk++){
      bf16x8 af[4], bf[8];
#pragma unroll
      for (int i=0;i<4;i++)
        af[i] = *(const bf16x8*)(As + (wr*64 + i*16 + lr)*64 + kk*32 + 8*g);
#pragma unroll
      for (int j=0;j<8;j++)
        bf[j] = *(const bf16x8*)(Bs + (wc*128 + j*16 + lr)*64 + kk*32 + 8*g);
#pragma unroll
      for (int mi=0;mi<4;mi++)
#pragma unroll
      for (int nj=0;nj<8;nj++)
        acc[mi][nj] = MFMA_BF16(af[mi], bf[nj], acc[mi][nj], 0,0,0);
    }
  }
  float bov[8], g2v[8], b2vv[8];
#pragma unroll
  for (int nj=0;nj<8;nj++){
    int n = wc*128 + nj*16 + lr;
    bov[nj] = bo[n]; g2v[nj] = g2[n]; b2vv[nj] = b2v[n];
  }
  // pass 1: hs = acc + bo + res (window-reverse scatter), partial row sums
#pragma unroll
  for (int mi=0;mi<4;mi++)
#pragma unroll
  for (int r=0;r<4;r++){
    int rowl = wr*64 + mi*16 + 4*g + r;
    int m = m0 + rowl;
    int bi = m >> 12, win = (m >> 6) & 63, p = m & 63;
    int hh = ((win >> 3)*8 + (p >> 3) + 4) & 63;
    int ww = ((win & 7)*8 + (p & 7) + 4) & 63;
    size_t base = ((size_t)bi*4096 + hh*64 + ww)*256;
    float s = 0.f, sq = 0.f;
#pragma unroll
    for (int nj=0;nj<8;nj++){
      int n = wc*128 + nj*16 + lr;
      float val = acc[mi][nj][r] + bov[nj] + hidden[base + n];
      hs_out[base + n] = val;
      acc[mi][nj][r] = val;
      s += val; sq += val*val;
    }
    for (int off=1; off<16; off<<=1){ s += __shfl_xor(s, off); sq += __shfl_xor(sq, off); }
    if (lr == 0){ part_s[rowl][wc] = s; part_q[rowl][wc] = sq; }
  }
  __syncthreads();
  // pass 2: LN2 -> y2 bf16 (token order)
#pragma unroll
  for (int mi=0;mi<4;mi++)
#pragma unroll
  for (int r=0;r<4;r++){
    int rowl = wr*64 + mi*16 + 4*g + r;
    int m = m0 + rowl;
    int bi = m >> 12, win = (m >> 6) & 63, p = m & 63;
    int hh = ((win >> 3)*8 + (p >> 3) + 4) & 63;
    int ww = ((win & 7)*8 + (p & 7) + 4) & 63;
    size_t base = ((size_t)bi*4096 + hh*64 + ww)*256;
    float sum = part_s[rowl][0] + part_s[rowl][1];
    float sqq = part_q[rowl][0] + part_q[rowl][1];
    float mean = sum*(1.f/256.f);
    float inv = rsqrtf(sqq*(1.f/256.f) - mean*mean + 1e-5f);
#pragma unroll
    for (int nj=0;nj<8;nj++){
      int n = wc*128 + nj*16 + lr;
      y2[base + n] = f2bf((acc[mi][nj][r]-mean)*inv*g2v[nj] + b2vv[nj]);
    }
  }
}

// ---------------- attention: one wave per (window, head) ----------------
__global__ __launch_bounds__(256) void k_attn(const u16* __restrict__ qkv, const float* __restrict__ fb,
                                              u16* __restrict__ outp){
  __shared__ __align__(16) u16 P[4][64*64];
  int lane = threadIdx.x & 63, wid = threadIdx.x >> 6;
  int g = lane >> 4, lr = lane & 15;
  int gw = blockIdx.x*4 + wid;
  int widx = gw >> 3, hh = gw & 7;
  const u16* qb = qkv + (size_t)(widx*8 + hh)*2048;
  const u16* kb = qb + 33554432u;
  const u16* vt = qb + 67108864u;
  bf16x8 qf[4], kf[4];
#pragma unroll
  for (int i=0;i<4;i++){
    qf[i] = *(const bf16x8*)(qb + (i*16 + lr)*32 + 8*g);
    kf[i] = *(const bf16x8*)(kb + (i*16 + lr)*32 + 8*g);
  }
  f32x4 acc[4][4] = {};
#pragma unroll
  for (int mi=0;mi<4;mi++)
#pragma unroll
  for (int nj=0;nj<4;nj++)
    acc[mi][nj] = MFMA_BF16(qf[mi], kf[nj], acc[mi][nj], 0,0,0);

  int win = widx & 63;
  int cls = (((win>>3)==7) ? 2 : 0) | (((win&7)==7) ? 1 : 0);
  const float* fbh = fb + (((size_t)cls*8 + hh) << 12);
#pragma unroll
  for (int mi=0;mi<4;mi++)
#pragma unroll
  for (int r=0;r<4;r++){
    int m = mi*16 + 4*g + r;
#pragma unroll
    for (int nj=0;nj<4;nj++)
      acc[mi][nj][r] += fbh[m*64 + nj*16 + lr];
  }
#pragma unroll
  for (int mi=0;mi<4;mi++)
#pragma unroll
  for (int r=0;r<4;r++){
    float mx = fmaxf(fmaxf(acc[mi][0][r], acc[mi][1][r]), fmaxf(acc[mi][2][r], acc[mi][3][r]));
    for (int off=1; off<16; off<<=1) mx = fmaxf(mx, __shfl_xor(mx, off));
    float s = 0.f;
#pragma unroll
    for (int nj=0;nj<4;nj++){ float e = __expf(acc[mi][nj][r]-mx); acc[mi][nj][r]=e; s+=e; }
    for (int off=1; off<16; off<<=1) s += __shfl_xor(s, off);
    float inv = 1.f/s;
#pragma unroll
    for (int nj=0;nj<4;nj++) acc[mi][nj][r] *= inv;
  }
  u16* Pw = P[wid];
#pragma unroll
  for (int mi=0;mi<4;mi++)
#pragma unroll
  for (int nj=0;nj<4;nj++)
#pragma unroll
  for (int r=0;r<4;r++){
    int row = mi*16 + 4*g + r;
    int blk = (nj*2 + (lr>>3)) ^ (row & 7);
    Pw[row*64 + blk*8 + (lr&7)] = f2bf(acc[mi][nj][r]);
  }
  __syncthreads();

  f32x4 acc2[4][2] = {};
#pragma unroll
  for (int ks=0; ks<2; ks++){
    bf16x8 vf[2];
#pragma unroll
    for (int nt=0; nt<2; nt++)
      vf[nt] = *(const bf16x8*)(vt + (nt*16 + lr)*64 + ks*32 + 8*g);
#pragma unroll
    for (int mi=0;mi<4;mi++){
      int row = mi*16 + lr;
      int blk = (ks*4 + g) ^ (row & 7);
      bf16x8 pf = *(const bf16x8*)(Pw + row*64 + blk*8);
      acc2[mi][0] = MFMA_BF16(pf, vf[0], acc2[mi][0], 0,0,0);
      acc2[mi][1] = MFMA_BF16(pf, vf[1], acc2[mi][1], 0,0,0);
    }
  }
#pragma unroll
  for (int mi=0;mi<4;mi++)
#pragma unroll
  for (int nt=0;nt<2;nt++)
#pragma unroll
  for (int r=0;r<4;r++)
    outp[((size_t)widx*64 + mi*16+4*g+r)*256 + hh*32 + nt*16 + lr] = f2bf(acc2[mi][nt][r]);
}

extern "C" void kernel_launch(void* const* d_in, const int* in_sizes, int n_in,
                              void* d_out, int out_size, void* d_ws, size_t ws_size,
                              hipStream_t stream){
  const float* hidden = (const float*)d_in[0];
  const float* ln1g = (const float*)d_in[1];
  const float* ln1b = (const float*)d_in[2];
  const float* wq   = (const float*)d_in[3];
  const float* bq   = (const float*)d_in[4];
  const float* wk   = (const float*)d_in[5];
  const float* bk   = (const float*)d_in[6];
  const float* wv   = (const float*)d_in[7];
  const float* bv   = (const float*)d_in[8];
  const float* btab = (const float*)d_in[9];
  const float* wo   = (const float*)d_in[10];
  const float* bo   = (const float*)d_in[11];
  const float* ln2g = (const float*)d_in[12];
  const float* ln2b = (const float*)d_in[13];
  const float* w1   = (const float*)d_in[14];
  const float* b1   = (const float*)d_in[15];
  const float* w2   = (const float*)d_in[16];
  const float* b2   = (const float*)d_in[17];
  float* out = (float*)d_out;

  char* ws = (char*)d_ws;
  const size_t MB = 1ull << 20;
  u16* xw    = (u16*)ws;                 // [0,64M): LN1 out -> attn out
  u16* qkv   = (u16*)(ws + 64*MB);       // [64M,256M): q|k|v
  u16* y1c   = qkv;                      // FC1 chunk out reuses q region (64MB)
  u16* y2ln  = (u16*)(ws + 128*MB);      // LN2 out reuses k region (64MB)
  u16* wqkvT = (u16*)(ws + 256*MB);      // bf16 weights, transposed [N][K]
  u16* woT   = wqkvT + 768*256;
  u16* w1T   = woT + 256*256;
  u16* w2T   = w1T + 1024*256;
  float* bqkv = (float*)(w2T + 1024*256);
  float* fbias = bqkv + 1024;            // 4*8*64*64 fp32 = 512KB

  // weight prep
  k_transpose<<<256, 256, 0, stream>>>(wq, wqkvT,          256, 256);
  k_transpose<<<256, 256, 0, stream>>>(wk, wqkvT + 65536,  256, 256);
  k_transpose<<<256, 256, 0, stream>>>(wv, wqkvT + 131072, 256, 256);
  k_transpose<<<256, 256, 0, stream>>>(wo, woT,            256, 256);
  k_transpose<<<1024,256, 0, stream>>>(w1, w1T,            256, 1024);
  k_transpose<<<1024,256, 0, stream>>>(w2, w2T,            1024, 256);
  k_concat_bias<<<1, 768, 0, stream>>>(bq, bk, bv, bqkv);
  k_bias<<<512, 256, 0, stream>>>(btab, fbias);

  // LN1 + shift + window partition
  k_ln1<<<32768, 256, 0, stream>>>(hidden, ln1g, ln1b, xw);
  // QKV projection
  k_gemm<0><<<dim3(6, 1024), 256, 0, stream>>>(xw, wqkvT, bqkv, nullptr, qkv, 256);
  // windowed attention (attn_out into xw region)
  k_attn<<<4096, 256, 0, stream>>>(qkv, fbias, xw);
  // O-proj + window reverse + residual -> hs (d_out), fused LN2 -> y2ln
  k_oproj<<<1024, 256, 0, stream>>>(xw, woT, bo, hidden, ln2g, ln2b, out, y2ln);
  // MLP in 4 M-chunks of 32768 rows
  for (int mc = 0; mc < 4; mc++){
    k_gemm<2><<<dim3(8, 256), 256, 0, stream>>>(y2ln + (size_t)mc*32768*256, w1T, b1, nullptr, y1c, 256);
    k_gemm<3><<<dim3(2, 256), 256, 0, stream>>>(y1c, w2T, b2,
                                                out + (size_t)mc*32768*256,
                                                out + (size_t)mc*32768*256, 1024);
  }
}

// Round 4
// 760.920 us; speedup vs baseline: 1.0409x; 1.0409x over previous
//
#include <hip/hip_runtime.h>
#include <hip/hip_bf16.h>
#include <math.h>

typedef unsigned short u16;
typedef __attribute__((ext_vector_type(8))) short bf16x8;
typedef __attribute__((ext_vector_type(4))) float f32x4;

#define MFMA_BF16 __builtin_amdgcn_mfma_f32_16x16x32_bf16

__device__ __forceinline__ u16 f2bf(float f){
  union { float f; unsigned u; } v; v.f = f;
  unsigned r = v.u + 0x7FFFu + ((v.u >> 16) & 1u);
  return (u16)(r >> 16);
}

__device__ __forceinline__ void gll16(const void* g, void* l){
  __builtin_amdgcn_global_load_lds(
      (const __attribute__((address_space(1))) unsigned int*)g,
      (__attribute__((address_space(3))) unsigned int*)l, 16, 0, 0);
}

// ---------------- weight prep: fp32 [K][N] -> bf16 [N][K] ----------------
__global__ void k_transpose(const float* __restrict__ src, u16* __restrict__ dst, int K, int N){
  int idx = blockIdx.x*256 + threadIdx.x;
  if (idx >= K*N) return;
  int n = idx / K, k = idx - n*K;
  dst[idx] = f2bf(src[(size_t)k*N + n]);
}

__global__ void k_concat_bias(const float* __restrict__ a, const float* __restrict__ b,
                              const float* __restrict__ c, float* __restrict__ o){
  int i = threadIdx.x;  // 768 threads
  o[i] = i < 256 ? a[i] : (i < 512 ? b[i-256] : c[i-512]);
}

// ---- fused rel-pos bias + shift mask table: fb[cls][head][m][n] ----
__global__ __launch_bounds__(256) void k_bias(const float* __restrict__ btab, float* __restrict__ fb){
  int idx = blockIdx.x*256 + threadIdx.x;   // 4*8*64*64 = 131072
  int n = idx & 63, m = (idx >> 6) & 63, hh = (idx >> 12) & 7, cls = idx >> 15;
  int r1=m>>3, c1=m&7, r2=n>>3, c2=n&7;
  float bv = btab[((r1-r2+7)*15 + (c1-c2+7))*8 + hh];
  int whe = cls>>1, wwe = cls&1;
  int a1 = (whe ? (r1<4?1:2) : 0)*3 + (wwe ? (c1<4?1:2) : 0);
  int a2 = (whe ? (r2<4?1:2) : 0)*3 + (wwe ? (c2<4?1:2) : 0);
  fb[idx] = bv + ((a1!=a2) ? -100.f : 0.f);
}

// ------------- LN1 + cyclic shift + window partition -> bf16 -------------
__global__ __launch_bounds__(256) void k_ln1(const float* __restrict__ x, const float* __restrict__ g,
                                             const float* __restrict__ b, u16* __restrict__ out){
  int lane = threadIdx.x & 63;
  int m = blockIdx.x*4 + (threadIdx.x >> 6);
  int bi = m >> 12, win = (m >> 6) & 63, p = m & 63;
  int h = ((win >> 3)*8 + (p >> 3) + 4) & 63;
  int w = ((win & 7)*8 + (p & 7) + 4) & 63;
  float4 v = ((const float4*)(x + ((size_t)bi*4096 + h*64 + w)*256))[lane];
  float s = v.x+v.y+v.z+v.w, sq = v.x*v.x+v.y*v.y+v.z*v.z+v.w*v.w;
  for (int off=32; off; off>>=1){ s += __shfl_xor(s, off); sq += __shfl_xor(sq, off); }
  float mean = s*(1.f/256.f);
  float inv = rsqrtf(sq*(1.f/256.f) - mean*mean + 1e-5f);
  float4 gg = ((const float4*)g)[lane], bb = ((const float4*)b)[lane];
  ushort4 o;
  o.x = f2bf((v.x-mean)*inv*gg.x + bb.x);
  o.y = f2bf((v.y-mean)*inv*gg.y + bb.y);
  o.z = f2bf((v.z-mean)*inv*gg.z + bb.z);
  o.w = f2bf((v.w-mean)*inv*gg.w + bb.w);
  ((ushort4*)(out + (size_t)m*256))[lane] = o;
}

// ---------------- GEMM: A[M][K] bf16 @ Bt[N][K] bf16, fp32 acc ----------------
// BM=BN=128, BK=64, 4 waves (2x2, 64x64 each), DOUBLE-BUFFERED global_load_lds
// (stage(t+1) issued right after the barrier, overlapping compute(t); the
// barrier's implicit vmcnt(0) waits for loads that had a full phase to fly).
// EPI 0: +bias(qkv concat), q scaled, scatter q/k [wh][tok][dim], v TRANSPOSED [wh][dim][tok]
// EPI 2: +b1, exact GELU, bf16 row-major out
// EPI 3: +b2, +hs residual, fp32 out
template<int EPI, bool SWZ>
__global__ __launch_bounds__(256) void k_gemm(const u16* __restrict__ A, const u16* __restrict__ Bt,
                                              const float* __restrict__ bias, const float* __restrict__ res,
                                              void* __restrict__ outp, int K){
  __shared__ __align__(16) u16 As[2][128*64];
  __shared__ __align__(16) u16 Bs[2][128*64];
  int tid = threadIdx.x, lane = tid & 63, wid = tid >> 6;
  int g = lane >> 4, lr = lane & 15;
  int wr = wid >> 1, wc = wid & 1;
  int bx, by;
  if constexpr (SWZ){
    int nwg = gridDim.x*gridDim.y;
    int bid = blockIdx.y*gridDim.x + blockIdx.x;
    int cpx = nwg >> 3;
    int swz = (bid & 7)*cpx + (bid >> 3);
    bx = swz % gridDim.x; by = swz / gridDim.x;
  } else { bx = blockIdx.x; by = blockIdx.y; }
  int m0 = by*128, n0 = bx*128;
  const u16* Aw = A + (size_t)m0*K;
  const u16* Bw = Bt + (size_t)n0*K;
  int srow = (lane >> 3);
  int scol = (lane & 7)*8;
  f32x4 acc[4][4] = {};
  int nt = K >> 6;

#define STAGE(b, k0)                                                    \
  _Pragma("unroll")                                                     \
  for (int c = 0; c < 4; c++){                                          \
    int chunk = wid*4 + c;                                              \
    int row = chunk*8 + srow;                                           \
    gll16(Aw + (size_t)row*K + (k0) + scol, &As[b][chunk*512]);         \
    gll16(Bw + (size_t)row*K + (k0) + scol, &Bs[b][chunk*512]);         \
  }

  STAGE(0, 0)
  for (int t = 0; t < nt; t++){
    __syncthreads();
    if (t+1 < nt){ STAGE((t+1)&1, (t+1)<<6) }
    int b = t & 1;
#pragma unroll
    for (int kk = 0; kk < 2; kk++){
      bf16x8 af[4], bf[4];
#pragma unroll
      for (int i=0;i<4;i++){
        af[i] = *(const bf16x8*)(&As[b][(wr*64 + i*16 + lr)*64 + kk*32 + 8*g]);
        bf[i] = *(const bf16x8*)(&Bs[b][(wc*64 + i*16 + lr)*64 + kk*32 + 8*g]);
      }
#pragma unroll
      for (int mi=0;mi<4;mi++)
#pragma unroll
      for (int nj=0;nj<4;nj++)
        acc[mi][nj] = MFMA_BF16(af[mi], bf[nj], acc[mi][nj], 0,0,0);
    }
  }
#undef STAGE

  const float scale = 0.1767766952966369f; // 32^-0.5
#pragma unroll
  for (int mi=0; mi<4; mi++)
#pragma unroll
  for (int nj=0; nj<4; nj++){
    int n = n0 + wc*64 + nj*16 + lr;
    if constexpr (EPI==0){
      int sec = n >> 8, ch = n & 255, head = ch >> 5, dim = ch & 31;
      if (sec < 2){
#pragma unroll
        for (int r=0; r<4; r++){
          int m = m0 + wr*64 + mi*16 + 4*g + r;
          float val = acc[mi][nj][r] + bias[n];
          if (sec == 0) val *= scale;
          size_t off = (size_t)sec*33554432u
                     + (((size_t)((m >> 6)*8 + head))*64 + (m & 63))*32 + dim;
          ((u16*)outp)[off] = f2bf(val);
        }
      } else {
        ushort4 pack;
        float bv = bias[n];
        pack.x = f2bf(acc[mi][nj][0] + bv);
        pack.y = f2bf(acc[mi][nj][1] + bv);
        pack.z = f2bf(acc[mi][nj][2] + bv);
        pack.w = f2bf(acc[mi][nj][3] + bv);
        int m_ = m0 + wr*64 + mi*16 + 4*g;
        size_t off = (size_t)2*33554432u
                   + (((size_t)((m_ >> 6)*8 + head))*32 + dim)*64 + (m_ & 63);
        *(ushort4*)((u16*)outp + off) = pack;
      }
    } else {
#pragma unroll
      for (int r=0; r<4; r++){
        int m = m0 + wr*64 + mi*16 + 4*g + r;
        float val = acc[mi][nj][r] + bias[n];
        if constexpr (EPI==2){
          float gv = 0.5f*val*(1.f + erff(val*0.70710678118654752f));
          ((u16*)outp)[(size_t)m*1024 + n] = f2bf(gv);
        } else {
          ((float*)outp)[(size_t)m*256 + n] = val + res[(size_t)m*256 + n];
        }
      }
    }
  }
}

// ------- O-proj (BN=256 full row) + window reverse + residual + fused LN2 -------
__global__ __launch_bounds__(256) void k_oproj(const u16* __restrict__ A, const u16* __restrict__ Bt,
                                               const float* __restrict__ bo, const float* __restrict__ hidden,
                                               const float* __restrict__ g2, const float* __restrict__ b2v,
                                               float* __restrict__ hs_out, u16* __restrict__ y2){
  __shared__ __align__(16) u16 As[128*64];
  __shared__ __align__(16) u16 Bs[256*64];
  __shared__ float part_s[128][2];
  __shared__ float part_q[128][2];
  int tid = threadIdx.x, lane = tid & 63, wid = tid >> 6;
  int g = lane >> 4, lr = lane & 15;
  int wr = wid >> 1, wc = wid & 1;
  int m0 = blockIdx.x*128;
  const u16* Aw = A + (size_t)m0*256;
  int srow = (lane >> 3);
  int scol = (lane & 7)*8;
  f32x4 acc[4][8] = {};
  for (int k0 = 0; k0 < 256; k0 += 64){
    __syncthreads();
#pragma unroll
    for (int c = 0; c < 4; c++){
      int chunk = wid*4 + c;
      int row = chunk*8 + srow;
      gll16(Aw + (size_t)row*256 + k0 + scol, As + chunk*512);
    }
#pragma unroll
    for (int c = 0; c < 8; c++){
      int chunk = wid*8 + c;
      int row = chunk*8 + srow;
      gll16(Bt + (size_t)row*256 + k0 + scol, Bs + chunk*512);
    }
    __syncthreads();
#pragma unroll
    for (int kk = 0; kk < 2; kk++){
      bf16x8 af[4], bf[8];
#pragma unroll
      for (int i=0;i<4;i++)
        af[i] = *(const bf16x8*)(As + (wr*64 + i*16 + lr)*64 + kk*32 + 8*g);
#pragma unroll
      for (int j=0;j<8;j++)
        bf[j] = *(const bf16x8*)(Bs + (wc*128 + j*16 + lr)*64 + kk*32 + 8*g);
#pragma unroll
      for (int mi=0;mi<4;mi++)
#pragma unroll
      for (int nj=0;nj<8;nj++)
        acc[mi][nj] = MFMA_BF16(af[mi], bf[nj], acc[mi][nj], 0,0,0);
    }
  }
  float bov[8], g2v[8], b2vv[8];
#pragma unroll
  for (int nj=0;nj<8;nj++){
    int n = wc*128 + nj*16 + lr;
    bov[nj] = bo[n]; g2v[nj] = g2[n]; b2vv[nj] = b2v[n];
  }
#pragma unroll
  for (int mi=0;mi<4;mi++)
#pragma unroll
  for (int r=0;r<4;r++){
    int rowl = wr*64 + mi*16 + 4*g + r;
    int m = m0 + rowl;
    int bi = m >> 12, win = (m >> 6) & 63, p = m & 63;
    int hh = ((win >> 3)*8 + (p >> 3) + 4) & 63;
    int ww = ((win & 7)*8 + (p & 7) + 4) & 63;
    size_t base = ((size_t)bi*4096 + hh*64 + ww)*256;
    float s = 0.f, sq = 0.f;
#pragma unroll
    for (int nj=0;nj<8;nj++){
      int n = wc*128 + nj*16 + lr;
      float val = acc[mi][nj][r] + bov[nj] + hidden[base + n];
      hs_out[base + n] = val;
      acc[mi][nj][r] = val;
      s += val; sq += val*val;
    }
    for (int off=1; off<16; off<<=1){ s += __shfl_xor(s, off); sq += __shfl_xor(sq, off); }
    if (lr == 0){ part_s[rowl][wc] = s; part_q[rowl][wc] = sq; }
  }
  __syncthreads();
#pragma unroll
  for (int mi=0;mi<4;mi++)
#pragma unroll
  for (int r=0;r<4;r++){
    int rowl = wr*64 + mi*16 + 4*g + r;
    int m = m0 + rowl;
    int bi = m >> 12, win = (m >> 6) & 63, p = m & 63;
    int hh = ((win >> 3)*8 + (p >> 3) + 4) & 63;
    int ww = ((win & 7)*8 + (p & 7) + 4) & 63;
    size_t base = ((size_t)bi*4096 + hh*64 + ww)*256;
    float sum = part_s[rowl][0] + part_s[rowl][1];
    float sqq = part_q[rowl][0] + part_q[rowl][1];
    float mean = sum*(1.f/256.f);
    float inv = rsqrtf(sqq*(1.f/256.f) - mean*mean + 1e-5f);
#pragma unroll
    for (int nj=0;nj<8;nj++){
      int n = wc*128 + nj*16 + lr;
      y2[base + n] = f2bf((acc[mi][nj][r]-mean)*inv*g2v[nj] + b2vv[nj]);
    }
  }
}

// ---------------- attention: one wave per (window, head) ----------------
__global__ __launch_bounds__(256) void k_attn(const u16* __restrict__ qkv, const float* __restrict__ fb,
                                              u16* __restrict__ outp){
  __shared__ __align__(16) u16 P[4][64*64];
  int lane = threadIdx.x & 63, wid = threadIdx.x >> 6;
  int g = lane >> 4, lr = lane & 15;
  int gw = blockIdx.x*4 + wid;
  int widx = gw >> 3, hh = gw & 7;
  const u16* qb = qkv + (size_t)(widx*8 + hh)*2048;
  const u16* kb = qb + 33554432u;
  const u16* vt = qb + 67108864u;
  bf16x8 qf[4], kf[4];
#pragma unroll
  for (int i=0;i<4;i++){
    qf[i] = *(const bf16x8*)(qb + (i*16 + lr)*32 + 8*g);
    kf[i] = *(const bf16x8*)(kb + (i*16 + lr)*32 + 8*g);
  }
  f32x4 acc[4][4] = {};
#pragma unroll
  for (int mi=0;mi<4;mi++)
#pragma unroll
  for (int nj=0;nj<4;nj++)
    acc[mi][nj] = MFMA_BF16(qf[mi], kf[nj], acc[mi][nj], 0,0,0);

  int win = widx & 63;
  int cls = (((win>>3)==7) ? 2 : 0) | (((win&7)==7) ? 1 : 0);
  const float* fbh = fb + (((size_t)cls*8 + hh) << 12);
#pragma unroll
  for (int mi=0;mi<4;mi++)
#pragma unroll
  for (int r=0;r<4;r++){
    int m = mi*16 + 4*g + r;
#pragma unroll
    for (int nj=0;nj<4;nj++)
      acc[mi][nj][r] += fbh[m*64 + nj*16 + lr];
  }
#pragma unroll
  for (int mi=0;mi<4;mi++)
#pragma unroll
  for (int r=0;r<4;r++){
    float mx = fmaxf(fmaxf(acc[mi][0][r], acc[mi][1][r]), fmaxf(acc[mi][2][r], acc[mi][3][r]));
    for (int off=1; off<16; off<<=1) mx = fmaxf(mx, __shfl_xor(mx, off));
    float s = 0.f;
#pragma unroll
    for (int nj=0;nj<4;nj++){ float e = __expf(acc[mi][nj][r]-mx); acc[mi][nj][r]=e; s+=e; }
    for (int off=1; off<16; off<<=1) s += __shfl_xor(s, off);
    float inv = 1.f/s;
#pragma unroll
    for (int nj=0;nj<4;nj++) acc[mi][nj][r] *= inv;
  }
  u16* Pw = P[wid];
#pragma unroll
  for (int mi=0;mi<4;mi++)
#pragma unroll
  for (int nj=0;nj<4;nj++)
#pragma unroll
  for (int r=0;r<4;r++){
    int row = mi*16 + 4*g + r;
    int blk = (nj*2 + (lr>>3)) ^ (row & 7);
    Pw[row*64 + blk*8 + (lr&7)] = f2bf(acc[mi][nj][r]);
  }
  __syncthreads();

  f32x4 acc2[4][2] = {};
#pragma unroll
  for (int ks=0; ks<2; ks++){
    bf16x8 vf[2];
#pragma unroll
    for (int nt=0; nt<2; nt++)
      vf[nt] = *(const bf16x8*)(vt + (nt*16 + lr)*64 + ks*32 + 8*g);
#pragma unroll
    for (int mi=0;mi<4;mi++){
      int row = mi*16 + lr;
      int blk = (ks*4 + g) ^ (row & 7);
      bf16x8 pf = *(const bf16x8*)(Pw + row*64 + blk*8);
      acc2[mi][0] = MFMA_BF16(pf, vf[0], acc2[mi][0], 0,0,0);
      acc2[mi][1] = MFMA_BF16(pf, vf[1], acc2[mi][1], 0,0,0);
    }
  }
#pragma unroll
  for (int mi=0;mi<4;mi++)
#pragma unroll
  for (int nt=0;nt<2;nt++)
#pragma unroll
  for (int r=0;r<4;r++)
    outp[((size_t)widx*64 + mi*16+4*g+r)*256 + hh*32 + nt*16 + lr] = f2bf(acc2[mi][nt][r]);
}

extern "C" void kernel_launch(void* const* d_in, const int* in_sizes, int n_in,
                              void* d_out, int out_size, void* d_ws, size_t ws_size,
                              hipStream_t stream){
  const float* hidden = (const float*)d_in[0];
  const float* ln1g = (const float*)d_in[1];
  const float* ln1b = (const float*)d_in[2];
  const float* wq   = (const float*)d_in[3];
  const float* bq   = (const float*)d_in[4];
  const float* wk   = (const float*)d_in[5];
  const float* bk   = (const float*)d_in[6];
  const float* wv   = (const float*)d_in[7];
  const float* bv   = (const float*)d_in[8];
  const float* btab = (const float*)d_in[9];
  const float* wo   = (const float*)d_in[10];
  const float* bo   = (const float*)d_in[11];
  const float* ln2g = (const float*)d_in[12];
  const float* ln2b = (const float*)d_in[13];
  const float* w1   = (const float*)d_in[14];
  const float* b1   = (const float*)d_in[15];
  const float* w2   = (const float*)d_in[16];
  const float* b2   = (const float*)d_in[17];
  float* out = (float*)d_out;

  char* ws = (char*)d_ws;
  const size_t MB = 1ull << 20;
  u16* xw    = (u16*)ws;                 // [0,64M): LN1 out -> attn out
  u16* qkv   = (u16*)(ws + 64*MB);       // [64M,256M): q|k|v
  u16* y1c   = qkv;                      // FC1 chunk out reuses q region (64MB)
  u16* y2ln  = (u16*)(ws + 128*MB);      // LN2 out reuses k region (64MB)
  u16* wqkvT = (u16*)(ws + 256*MB);      // bf16 weights, transposed [N][K]
  u16* woT   = wqkvT + 768*256;
  u16* w1T   = woT + 256*256;
  u16* w2T   = w1T + 1024*256;
  float* bqkv = (float*)(w2T + 1024*256);
  float* fbias = bqkv + 1024;            // 4*8*64*64 fp32 = 512KB

  // weight prep
  k_transpose<<<256, 256, 0, stream>>>(wq, wqkvT,          256, 256);
  k_transpose<<<256, 256, 0, stream>>>(wk, wqkvT + 65536,  256, 256);
  k_transpose<<<256, 256, 0, stream>>>(wv, wqkvT + 131072, 256, 256);
  k_transpose<<<256, 256, 0, stream>>>(wo, woT,            256, 256);
  k_transpose<<<1024,256, 0, stream>>>(w1, w1T,            256, 1024);
  k_transpose<<<1024,256, 0, stream>>>(w2, w2T,            1024, 256);
  k_concat_bias<<<1, 768, 0, stream>>>(bq, bk, bv, bqkv);
  k_bias<<<512, 256, 0, stream>>>(btab, fbias);

  // LN1 + shift + window partition
  k_ln1<<<32768, 256, 0, stream>>>(hidden, ln1g, ln1b, xw);
  // QKV projection (no XCD swizzle: scatter-write bound, swizzle hurt -19us)
  k_gemm<0,false><<<dim3(6, 1024), 256, 0, stream>>>(xw, wqkvT, bqkv, nullptr, qkv, 256);
  // windowed attention (attn_out into xw region)
  k_attn<<<4096, 256, 0, stream>>>(qkv, fbias, xw);
  // O-proj + window reverse + residual -> hs (d_out), fused LN2 -> y2ln
  k_oproj<<<1024, 256, 0, stream>>>(xw, woT, bo, hidden, ln2g, ln2b, out, y2ln);
  // MLP in 4 M-chunks of 32768 rows
  for (int mc = 0; mc < 4; mc++){
    k_gemm<2,true><<<dim3(8, 256), 256, 0, stream>>>(y2ln + (size_t)mc*32768*256, w1T, b1, nullptr, y1c, 256);
    k_gemm<3,true><<<dim3(2, 256), 256, 0, stream>>>(y1c, w2T, b2,
                                                     out + (size_t)mc*32768*256,
                                                     out + (size_t)mc*32768*256, 1024);
  }
}

// Round 5
// 683.454 us; speedup vs baseline: 1.1589x; 1.1133x over previous
//
#include <hip/hip_runtime.h>
#include <hip/hip_bf16.h>
#include <math.h>

typedef unsigned short u16;
typedef __attribute__((ext_vector_type(8))) short bf16x8;
typedef __attribute__((ext_vector_type(4))) float f32x4;

#define MFMA_BF16 __builtin_amdgcn_mfma_f32_16x16x32_bf16

__device__ __forceinline__ u16 f2bf(float f){
  union { float f; unsigned u; } v; v.f = f;
  unsigned r = v.u + 0x7FFFu + ((v.u >> 16) & 1u);
  return (u16)(r >> 16);
}

__device__ __forceinline__ void gll16(const void* g, void* l){
  __builtin_amdgcn_global_load_lds(
      (const __attribute__((address_space(1))) unsigned int*)g,
      (__attribute__((address_space(3))) unsigned int*)l, 16, 0, 0);
}

// ---------------- weight prep: fp32 [K][N] -> bf16 [N][K] ----------------
__global__ void k_transpose(const float* __restrict__ src, u16* __restrict__ dst, int K, int N){
  int idx = blockIdx.x*256 + threadIdx.x;
  if (idx >= K*N) return;
  int n = idx / K, k = idx - n*K;
  dst[idx] = f2bf(src[(size_t)k*N + n]);
}

__global__ void k_concat_bias(const float* __restrict__ a, const float* __restrict__ b,
                              const float* __restrict__ c, float* __restrict__ o){
  int i = threadIdx.x;  // 768 threads
  o[i] = i < 256 ? a[i] : (i < 512 ? b[i-256] : c[i-512]);
}

// ---- fused rel-pos bias + shift mask table: fb[cls][head][m][n] ----
__global__ __launch_bounds__(256) void k_bias(const float* __restrict__ btab, float* __restrict__ fb){
  int idx = blockIdx.x*256 + threadIdx.x;   // 4*8*64*64 = 131072
  int n = idx & 63, m = (idx >> 6) & 63, hh = (idx >> 12) & 7, cls = idx >> 15;
  int r1=m>>3, c1=m&7, r2=n>>3, c2=n&7;
  float bv = btab[((r1-r2+7)*15 + (c1-c2+7))*8 + hh];
  int whe = cls>>1, wwe = cls&1;
  int a1 = (whe ? (r1<4?1:2) : 0)*3 + (wwe ? (c1<4?1:2) : 0);
  int a2 = (whe ? (r2<4?1:2) : 0)*3 + (wwe ? (c2<4?1:2) : 0);
  fb[idx] = bv + ((a1!=a2) ? -100.f : 0.f);
}

// ------------- LN1 + cyclic shift + window partition -> bf16 -------------
__global__ __launch_bounds__(256) void k_ln1(const float* __restrict__ x, const float* __restrict__ g,
                                             const float* __restrict__ b, u16* __restrict__ out){
  int lane = threadIdx.x & 63;
  int m = blockIdx.x*4 + (threadIdx.x >> 6);
  int bi = m >> 12, win = (m >> 6) & 63, p = m & 63;
  int h = ((win >> 3)*8 + (p >> 3) + 4) & 63;
  int w = ((win & 7)*8 + (p & 7) + 4) & 63;
  float4 v = ((const float4*)(x + ((size_t)bi*4096 + h*64 + w)*256))[lane];
  float s = v.x+v.y+v.z+v.w, sq = v.x*v.x+v.y*v.y+v.z*v.z+v.w*v.w;
  for (int off=32; off; off>>=1){ s += __shfl_xor(s, off); sq += __shfl_xor(sq, off); }
  float mean = s*(1.f/256.f);
  float inv = rsqrtf(sq*(1.f/256.f) - mean*mean + 1e-5f);
  float4 gg = ((const float4*)g)[lane], bb = ((const float4*)b)[lane];
  ushort4 o;
  o.x = f2bf((v.x-mean)*inv*gg.x + bb.x);
  o.y = f2bf((v.y-mean)*inv*gg.y + bb.y);
  o.z = f2bf((v.z-mean)*inv*gg.z + bb.z);
  o.w = f2bf((v.w-mean)*inv*gg.w + bb.w);
  ((ushort4*)(out + (size_t)m*256))[lane] = o;
}

// ============ 256x256-tile GEMM engine: A[M][K] @ Bt[N][K], fp32 acc ============
// 8 waves (2M x 4N), per-wave 128x64 (8x4 frags), BK=64, dbuf, XOR-swizzled LDS
// (linear gll_lds dest + inverse-swizzled global source + swizzled ds_read).
// EPI 0: +bias(qkv concat), q scaled, scatter q/k [wh][tok][dim], v [wh][dim][tok]
// EPI 2: +b1, exact GELU, bf16 row-major out [m][1024]
// EPI 3: +b2, +hs residual (fp32), fp32 out
#define GSTAGE(buf, k0)                                                  \
  _Pragma("unroll")                                                      \
  for (int c = 0; c < 4; c++){                                           \
    int row = c*64 + srow;                                               \
    gll16(Aw + (size_t)row*K + (k0) + (scb>>1), &As[buf][c*4096 + tid*8]); \
    gll16(Bw + (size_t)row*K + (k0) + (scb>>1), &Bs[buf][c*4096 + tid*8]); \
  }

template<int EPI, bool SWZ>
__global__ __launch_bounds__(512, 2) void k_gemm256(const u16* __restrict__ A, const u16* __restrict__ Bt,
                                                    const float* __restrict__ bias, const float* __restrict__ res,
                                                    void* __restrict__ outp, int K){
  __shared__ __align__(16) u16 As[2][16384];
  __shared__ __align__(16) u16 Bs[2][16384];
  int tid = threadIdx.x, lane = tid & 63, wid = tid >> 6;
  int g = lane >> 4, lr = lane & 15;
  int wr = wid >> 2, wc = wid & 3;
  int bx, by;
  if constexpr (SWZ){
    int nwg = gridDim.x*gridDim.y;
    int bid = blockIdx.y*gridDim.x + blockIdx.x;
    int cpx = nwg >> 3;
    int swz = (bid & 7)*cpx + (bid >> 3);
    bx = swz % gridDim.x; by = swz / gridDim.x;
  } else { bx = blockIdx.x; by = blockIdx.y; }
  int m0 = by*256, n0 = bx*256;
  const u16* Aw = A + (size_t)m0*K;
  const u16* Bw = Bt + (size_t)n0*K;
  int srow = tid >> 3;                              // LDS row within 64-row chunk
  int scb  = ((tid & 7)*16) ^ ((srow & 7) << 4);    // inverse-swizzled source byte col
  f32x4 acc[8][4] = {};
  int nt = K >> 6;

  GSTAGE(0, 0)
  for (int t = 0; t < nt; t++){
    __syncthreads();
    if (t+1 < nt){ GSTAGE((t+1)&1, (t+1)<<6) }
    int b = t & 1;
#pragma unroll
    for (int kk = 0; kk < 2; kk++){
      int cbr = (kk*64 + 16*g) ^ ((lr & 7) << 4);   // swizzled read byte col
      bf16x8 af[8], bf[4];
#pragma unroll
      for (int i=0;i<8;i++)
        af[i] = *(const bf16x8*)(&As[b][(wr*128 + i*16 + lr)*64 + (cbr>>1)]);
#pragma unroll
      for (int j=0;j<4;j++)
        bf[j] = *(const bf16x8*)(&Bs[b][(wc*64 + j*16 + lr)*64 + (cbr>>1)]);
#pragma unroll
      for (int mi=0;mi<8;mi++)
#pragma unroll
      for (int nj=0;nj<4;nj++)
        acc[mi][nj] = MFMA_BF16(af[mi], bf[nj], acc[mi][nj], 0,0,0);
    }
  }

  const float scale = 0.1767766952966369f; // 32^-0.5
#pragma unroll
  for (int mi=0; mi<8; mi++)
#pragma unroll
  for (int nj=0; nj<4; nj++){
    int n = n0 + wc*64 + nj*16 + lr;
    if constexpr (EPI==0){
      int sec = n >> 8, ch = n & 255, head = ch >> 5, dim = ch & 31;
      if (sec < 2){
#pragma unroll
        for (int r=0; r<4; r++){
          int m = m0 + wr*128 + mi*16 + 4*g + r;
          float val = acc[mi][nj][r] + bias[n];
          if (sec == 0) val *= scale;
          size_t off = (size_t)sec*33554432u
                     + (((size_t)((m >> 6)*8 + head))*64 + (m & 63))*32 + dim;
          ((u16*)outp)[off] = f2bf(val);
        }
      } else {
        ushort4 pack;
        float bv = bias[n];
        pack.x = f2bf(acc[mi][nj][0] + bv);
        pack.y = f2bf(acc[mi][nj][1] + bv);
        pack.z = f2bf(acc[mi][nj][2] + bv);
        pack.w = f2bf(acc[mi][nj][3] + bv);
        int m_ = m0 + wr*128 + mi*16 + 4*g;
        size_t off = (size_t)2*33554432u
                   + (((size_t)((m_ >> 6)*8 + head))*32 + dim)*64 + (m_ & 63);
        *(ushort4*)((u16*)outp + off) = pack;
      }
    } else {
#pragma unroll
      for (int r=0; r<4; r++){
        int m = m0 + wr*128 + mi*16 + 4*g + r;
        float val = acc[mi][nj][r] + bias[n];
        if constexpr (EPI==2){
          float gv = 0.5f*val*(1.f + erff(val*0.70710678118654752f));
          ((u16*)outp)[(size_t)m*1024 + n] = f2bf(gv);
        } else {
          ((float*)outp)[(size_t)m*256 + n] = val + res[(size_t)m*256 + n];
        }
      }
    }
  }
}

// ------- O-proj 256x256 (BN=256 = full row) + window reverse + residual + fused LN2 -------
__global__ __launch_bounds__(512, 2) void k_oproj(const u16* __restrict__ A, const u16* __restrict__ Bt,
                                                  const float* __restrict__ bo, const float* __restrict__ hidden,
                                                  const float* __restrict__ g2, const float* __restrict__ b2v,
                                                  float* __restrict__ hs_out, u16* __restrict__ y2){
  __shared__ __align__(16) u16 As[2][16384];
  __shared__ __align__(16) u16 Bs[2][16384];
  __shared__ float part_s[256][4];
  __shared__ float part_q[256][4];
  const int K = 256;
  int tid = threadIdx.x, lane = tid & 63, wid = tid >> 6;
  int g = lane >> 4, lr = lane & 15;
  int wr = wid >> 2, wc = wid & 3;
  int m0 = blockIdx.x*256;
  const u16* Aw = A + (size_t)m0*K;
  const u16* Bw = Bt;
  int srow = tid >> 3;
  int scb  = ((tid & 7)*16) ^ ((srow & 7) << 4);
  f32x4 acc[8][4] = {};
  int nt = 4;

  GSTAGE(0, 0)
  for (int t = 0; t < nt; t++){
    __syncthreads();
    if (t+1 < nt){ GSTAGE((t+1)&1, (t+1)<<6) }
    int b = t & 1;
#pragma unroll
    for (int kk = 0; kk < 2; kk++){
      int cbr = (kk*64 + 16*g) ^ ((lr & 7) << 4);
      bf16x8 af[8], bf[4];
#pragma unroll
      for (int i=0;i<8;i++)
        af[i] = *(const bf16x8*)(&As[b][(wr*128 + i*16 + lr)*64 + (cbr>>1)]);
#pragma unroll
      for (int j=0;j<4;j++)
        bf[j] = *(const bf16x8*)(&Bs[b][(wc*64 + j*16 + lr)*64 + (cbr>>1)]);
#pragma unroll
      for (int mi=0;mi<8;mi++)
#pragma unroll
      for (int nj=0;nj<4;nj++)
        acc[mi][nj] = MFMA_BF16(af[mi], bf[nj], acc[mi][nj], 0,0,0);
    }
  }

  float bov[4], g2v[4], b2vv[4];
#pragma unroll
  for (int nj=0;nj<4;nj++){
    int n = wc*64 + nj*16 + lr;
    bov[nj] = bo[n]; g2v[nj] = g2[n]; b2vv[nj] = b2v[n];
  }
  // pass 1: hs = acc + bo + res (window-reverse gather/scatter), partial row sums
#pragma unroll
  for (int mi=0;mi<8;mi++)
#pragma unroll
  for (int r=0;r<4;r++){
    int rowl = wr*128 + mi*16 + 4*g + r;
    int m = m0 + rowl;
    int bi = m >> 12, win = (m >> 6) & 63, p = m & 63;
    int hh = ((win >> 3)*8 + (p >> 3) + 4) & 63;
    int ww = ((win & 7)*8 + (p & 7) + 4) & 63;
    size_t base = ((size_t)bi*4096 + hh*64 + ww)*256;
    float s = 0.f, sq = 0.f;
#pragma unroll
    for (int nj=0;nj<4;nj++){
      int n = wc*64 + nj*16 + lr;
      float val = acc[mi][nj][r] + bov[nj] + hidden[base + n];
      hs_out[base + n] = val;
      acc[mi][nj][r] = val;
      s += val; sq += val*val;
    }
    for (int off=1; off<16; off<<=1){ s += __shfl_xor(s, off); sq += __shfl_xor(sq, off); }
    if (lr == 0){ part_s[rowl][wc] = s; part_q[rowl][wc] = sq; }
  }
  __syncthreads();
  // pass 2: LN2 -> y2 bf16 (token order)
#pragma unroll
  for (int mi=0;mi<8;mi++)
#pragma unroll
  for (int r=0;r<4;r++){
    int rowl = wr*128 + mi*16 + 4*g + r;
    int m = m0 + rowl;
    int bi = m >> 12, win = (m >> 6) & 63, p = m & 63;
    int hh = ((win >> 3)*8 + (p >> 3) + 4) & 63;
    int ww = ((win & 7)*8 + (p & 7) + 4) & 63;
    size_t base = ((size_t)bi*4096 + hh*64 + ww)*256;
    float sum = part_s[rowl][0] + part_s[rowl][1] + part_s[rowl][2] + part_s[rowl][3];
    float sqq = part_q[rowl][0] + part_q[rowl][1] + part_q[rowl][2] + part_q[rowl][3];
    float mean = sum*(1.f/256.f);
    float inv = rsqrtf(sqq*(1.f/256.f) - mean*mean + 1e-5f);
#pragma unroll
    for (int nj=0;nj<4;nj++){
      int n = wc*64 + nj*16 + lr;
      y2[base + n] = f2bf((acc[mi][nj][r]-mean)*inv*g2v[nj] + b2vv[nj]);
    }
  }
}

// ---------------- attention: one wave per (window, head) ----------------
__global__ __launch_bounds__(256) void k_attn(const u16* __restrict__ qkv, const float* __restrict__ fb,
                                              u16* __restrict__ outp){
  __shared__ __align__(16) u16 P[4][64*64];
  int lane = threadIdx.x & 63, wid = threadIdx.x >> 6;
  int g = lane >> 4, lr = lane & 15;
  int gw = blockIdx.x*4 + wid;
  int widx = gw >> 3, hh = gw & 7;
  const u16* qb = qkv + (size_t)(widx*8 + hh)*2048;
  const u16* kb = qb + 33554432u;
  const u16* vt = qb + 67108864u;
  bf16x8 qf[4], kf[4];
#pragma unroll
  for (int i=0;i<4;i++){
    qf[i] = *(const bf16x8*)(qb + (i*16 + lr)*32 + 8*g);
    kf[i] = *(const bf16x8*)(kb + (i*16 + lr)*32 + 8*g);
  }
  f32x4 acc[4][4] = {};
#pragma unroll
  for (int mi=0;mi<4;mi++)
#pragma unroll
  for (int nj=0;nj<4;nj++)
    acc[mi][nj] = MFMA_BF16(qf[mi], kf[nj], acc[mi][nj], 0,0,0);

  int win = widx & 63;
  int cls = (((win>>3)==7) ? 2 : 0) | (((win&7)==7) ? 1 : 0);
  const float* fbh = fb + (((size_t)cls*8 + hh) << 12);
#pragma unroll
  for (int mi=0;mi<4;mi++)
#pragma unroll
  for (int r=0;r<4;r++){
    int m = mi*16 + 4*g + r;
#pragma unroll
    for (int nj=0;nj<4;nj++)
      acc[mi][nj][r] += fbh[m*64 + nj*16 + lr];
  }
#pragma unroll
  for (int mi=0;mi<4;mi++)
#pragma unroll
  for (int r=0;r<4;r++){
    float mx = fmaxf(fmaxf(acc[mi][0][r], acc[mi][1][r]), fmaxf(acc[mi][2][r], acc[mi][3][r]));
    for (int off=1; off<16; off<<=1) mx = fmaxf(mx, __shfl_xor(mx, off));
    float s = 0.f;
#pragma unroll
    for (int nj=0;nj<4;nj++){ float e = __expf(acc[mi][nj][r]-mx); acc[mi][nj][r]=e; s+=e; }
    for (int off=1; off<16; off<<=1) s += __shfl_xor(s, off);
    float inv = 1.f/s;
#pragma unroll
    for (int nj=0;nj<4;nj++) acc[mi][nj][r] *= inv;
  }
  u16* Pw = P[wid];
#pragma unroll
  for (int mi=0;mi<4;mi++)
#pragma unroll
  for (int nj=0;nj<4;nj++)
#pragma unroll
  for (int r=0;r<4;r++){
    int row = mi*16 + 4*g + r;
    int blk = (nj*2 + (lr>>3)) ^ (row & 7);
    Pw[row*64 + blk*8 + (lr&7)] = f2bf(acc[mi][nj][r]);
  }
  __syncthreads();

  f32x4 acc2[4][2] = {};
#pragma unroll
  for (int ks=0; ks<2; ks++){
    bf16x8 vf[2];
#pragma unroll
    for (int nt=0; nt<2; nt++)
      vf[nt] = *(const bf16x8*)(vt + (nt*16 + lr)*64 + ks*32 + 8*g);
#pragma unroll
    for (int mi=0;mi<4;mi++){
      int row = mi*16 + lr;
      int blk = (ks*4 + g) ^ (row & 7);
      bf16x8 pf = *(const bf16x8*)(Pw + row*64 + blk*8);
      acc2[mi][0] = MFMA_BF16(pf, vf[0], acc2[mi][0], 0,0,0);
      acc2[mi][1] = MFMA_BF16(pf, vf[1], acc2[mi][1], 0,0,0);
    }
  }
#pragma unroll
  for (int mi=0;mi<4;mi++)
#pragma unroll
  for (int nt=0;nt<2;nt++)
#pragma unroll
  for (int r=0;r<4;r++)
    outp[((size_t)widx*64 + mi*16+4*g+r)*256 + hh*32 + nt*16 + lr] = f2bf(acc2[mi][nt][r]);
}

extern "C" void kernel_launch(void* const* d_in, const int* in_sizes, int n_in,
                              void* d_out, int out_size, void* d_ws, size_t ws_size,
                              hipStream_t stream){
  const float* hidden = (const float*)d_in[0];
  const float* ln1g = (const float*)d_in[1];
  const float* ln1b = (const float*)d_in[2];
  const float* wq   = (const float*)d_in[3];
  const float* bq   = (const float*)d_in[4];
  const float* wk   = (const float*)d_in[5];
  const float* bk   = (const float*)d_in[6];
  const float* wv   = (const float*)d_in[7];
  const float* bv   = (const float*)d_in[8];
  const float* btab = (const float*)d_in[9];
  const float* wo   = (const float*)d_in[10];
  const float* bo   = (const float*)d_in[11];
  const float* ln2g = (const float*)d_in[12];
  const float* ln2b = (const float*)d_in[13];
  const float* w1   = (const float*)d_in[14];
  const float* b1   = (const float*)d_in[15];
  const float* w2   = (const float*)d_in[16];
  const float* b2   = (const float*)d_in[17];
  float* out = (float*)d_out;

  char* ws = (char*)d_ws;
  const size_t MB = 1ull << 20;
  u16* xw    = (u16*)ws;                 // [0,64M): LN1 out -> attn out
  u16* qkv   = (u16*)(ws + 64*MB);       // [64M,256M): q|k|v
  u16* y1c   = qkv;                      // FC1 chunk out (128MB) reuses q+k region
  u16* y2ln  = (u16*)(ws + 192*MB);      // LN2 out (64MB) reuses v region
  u16* wqkvT = (u16*)(ws + 256*MB);      // bf16 weights, transposed [N][K]
  u16* woT   = wqkvT + 768*256;
  u16* w1T   = woT + 256*256;
  u16* w2T   = w1T + 1024*256;
  float* bqkv = (float*)(w2T + 1024*256);
  float* fbias = bqkv + 1024;            // 4*8*64*64 fp32 = 512KB

  // weight prep
  k_transpose<<<256, 256, 0, stream>>>(wq, wqkvT,          256, 256);
  k_transpose<<<256, 256, 0, stream>>>(wk, wqkvT + 65536,  256, 256);
  k_transpose<<<256, 256, 0, stream>>>(wv, wqkvT + 131072, 256, 256);
  k_transpose<<<256, 256, 0, stream>>>(wo, woT,            256, 256);
  k_transpose<<<1024,256, 0, stream>>>(w1, w1T,            256, 1024);
  k_transpose<<<1024,256, 0, stream>>>(w2, w2T,            1024, 256);
  k_concat_bias<<<1, 768, 0, stream>>>(bq, bk, bv, bqkv);
  k_bias<<<512, 256, 0, stream>>>(btab, fbias);

  // LN1 + shift + window partition
  k_ln1<<<32768, 256, 0, stream>>>(hidden, ln1g, ln1b, xw);
  // QKV projection (256-tile engine; XCD swizzle: 3 column-siblings share A via L2)
  k_gemm256<0,true><<<dim3(3, 512), 512, 0, stream>>>(xw, wqkvT, bqkv, nullptr, qkv, 256);
  // windowed attention (attn_out into xw region)
  k_attn<<<4096, 256, 0, stream>>>(qkv, fbias, xw);
  // O-proj + window reverse + residual -> hs (d_out), fused LN2 -> y2ln
  k_oproj<<<512, 512, 0, stream>>>(xw, woT, bo, hidden, ln2g, ln2b, out, y2ln);
  // MLP in 2 M-chunks of 65536 rows (y1 reuses dead q/k region, 128MB)
  for (int mc = 0; mc < 2; mc++){
    k_gemm256<2,true><<<dim3(4, 256), 512, 0, stream>>>(y2ln + (size_t)mc*65536*256, w1T, b1, nullptr, y1c, 256);
    k_gemm256<3,false><<<dim3(1, 256), 512, 0, stream>>>(y1c, w2T, b2,
                                                         out + (size_t)mc*65536*256,
                                                         out + (size_t)mc*65536*256, 1024);
  }
}

// Round 6
// 673.200 us; speedup vs baseline: 1.1765x; 1.0152x over previous
//
#include <hip/hip_runtime.h>
#include <hip/hip_bf16.h>
#include <math.h>

typedef unsigned short u16;
typedef __attribute__((ext_vector_type(8))) short bf16x8;
typedef __attribute__((ext_vector_type(8))) unsigned short u16x8;
typedef __attribute__((ext_vector_type(4))) float f32x4;

#define MFMA_BF16 __builtin_amdgcn_mfma_f32_16x16x32_bf16

__device__ __forceinline__ u16 f2bf(float f){
  union { float f; unsigned u; } v; v.f = f;
  unsigned r = v.u + 0x7FFFu + ((v.u >> 16) & 1u);
  return (u16)(r >> 16);
}

__device__ __forceinline__ void gll16(const void* g, void* l){
  __builtin_amdgcn_global_load_lds(
      (const __attribute__((address_space(1))) unsigned int*)g,
      (__attribute__((address_space(3))) unsigned int*)l, 16, 0, 0);
}

// ---------------- weight prep: fp32 [K][N] -> bf16 [N][K] ----------------
__global__ void k_transpose(const float* __restrict__ src, u16* __restrict__ dst, int K, int N){
  int idx = blockIdx.x*256 + threadIdx.x;
  if (idx >= K*N) return;
  int n = idx / K, k = idx - n*K;
  dst[idx] = f2bf(src[(size_t)k*N + n]);
}

__global__ void k_concat_bias(const float* __restrict__ a, const float* __restrict__ b,
                              const float* __restrict__ c, float* __restrict__ o){
  int i = threadIdx.x;  // 768 threads
  o[i] = i < 256 ? a[i] : (i < 512 ? b[i-256] : c[i-512]);
}

// ---- fused rel-pos bias + shift mask table: fb[cls][head][m][n] ----
__global__ __launch_bounds__(256) void k_bias(const float* __restrict__ btab, float* __restrict__ fb){
  int idx = blockIdx.x*256 + threadIdx.x;   // 4*8*64*64 = 131072
  int n = idx & 63, m = (idx >> 6) & 63, hh = (idx >> 12) & 7, cls = idx >> 15;
  int r1=m>>3, c1=m&7, r2=n>>3, c2=n&7;
  float bv = btab[((r1-r2+7)*15 + (c1-c2+7))*8 + hh];
  int whe = cls>>1, wwe = cls&1;
  int a1 = (whe ? (r1<4?1:2) : 0)*3 + (wwe ? (c1<4?1:2) : 0);
  int a2 = (whe ? (r2<4?1:2) : 0)*3 + (wwe ? (c2<4?1:2) : 0);
  fb[idx] = bv + ((a1!=a2) ? -100.f : 0.f);
}

// ======== FUSED LN1 + QKV-projection + windowed attention ========
// One block per window (2048). 8 waves = 8 heads. q/k/v never touch HBM.
// LDS (u16 units): xb[64][256] swizzled at [0,16384);
//   per-wave region base 16384 + wid*7424: q[64][40], k[64][40], vT[32][72];
//   P[64][72] aliases q+k after QK^T.
__global__ __launch_bounds__(512) void k_fattn(const float* __restrict__ hidden,
    const float* __restrict__ g1, const float* __restrict__ b1f,
    const u16* __restrict__ wqkvT, const float* __restrict__ bqkv,
    const float* __restrict__ fb, u16* __restrict__ outp)
{
  __shared__ __align__(16) u16 lds[75776];   // 151552 B
  int tid = threadIdx.x, lane = tid & 63, wid = tid >> 6;
  int lg = lane >> 4, lr = lane & 15;
  int gw = blockIdx.x;
  int bi = gw >> 6, win = gw & 63, wh = win >> 3, wwi = win & 7;

  // ---- Phase 1: LN1 + cyclic-shift gather -> xb (chunk-XOR swizzled) ----
  {
    int t = wid*8 + (lane >> 3);           // token 0..63
    int j = lane & 7;                      // 32-channel chunk
    int hh_ = (wh*8 + (t >> 3) + 4) & 63;
    int ww_ = (wwi*8 + (t & 7) + 4) & 63;
    const float4* row = (const float4*)(hidden + ((size_t)bi*4096 + hh_*64 + ww_)*256) + j*8;
    float4 v[8]; float s = 0.f, sq = 0.f;
#pragma unroll
    for (int i=0;i<8;i++){
      v[i] = row[i];
      s  += v[i].x+v[i].y+v[i].z+v[i].w;
      sq += v[i].x*v[i].x+v[i].y*v[i].y+v[i].z*v[i].z+v[i].w*v[i].w;
    }
    s += __shfl_xor(s,1); sq += __shfl_xor(sq,1);
    s += __shfl_xor(s,2); sq += __shfl_xor(sq,2);
    s += __shfl_xor(s,4); sq += __shfl_xor(sq,4);
    float mean = s*(1.f/256.f);
    float inv = rsqrtf(sq*(1.f/256.f) - mean*mean + 1e-5f);
    const float4* gg = (const float4*)g1 + j*8;
    const float4* bb = (const float4*)b1f + j*8;
#pragma unroll
    for (int i2=0;i2<4;i2++){
      float4 a0=v[2*i2], a1=v[2*i2+1];
      float4 g0=gg[2*i2], g1_=gg[2*i2+1];
      float4 b0=bb[2*i2], b1_=bb[2*i2+1];
      u16x8 pk;
      pk[0]=f2bf((a0.x-mean)*inv*g0.x+b0.x); pk[1]=f2bf((a0.y-mean)*inv*g0.y+b0.y);
      pk[2]=f2bf((a0.z-mean)*inv*g0.z+b0.z); pk[3]=f2bf((a0.w-mean)*inv*g0.w+b0.w);
      pk[4]=f2bf((a1.x-mean)*inv*g1_.x+b1_.x); pk[5]=f2bf((a1.y-mean)*inv*g1_.y+b1_.y);
      pk[6]=f2bf((a1.z-mean)*inv*g1_.z+b1_.z); pk[7]=f2bf((a1.w-mean)*inv*g1_.w+b1_.w);
      int c = (j*4+i2) ^ (t & 7);
      *(u16x8*)(&lds[t*256 + c*8]) = pk;
    }
  }
  __syncthreads();

  // ---- Phase 2: mini-GEMM q/k/v for head `wid` (weights from L2) ----
  f32x4 qa[4][2]={}, ka[4][2]={}, va[4][2]={};
#pragma unroll
  for (int ks=0; ks<8; ks++){
    bf16x8 af[4];
#pragma unroll
    for (int mi=0;mi<4;mi++){
      int tok = mi*16+lr;
      af[mi] = *(const bf16x8*)(&lds[tok*256 + (((ks*4+lg) ^ (tok&7))*8)]);
    }
#pragma unroll
    for (int nj=0;nj<2;nj++){
      const u16* wr_ = wqkvT + (size_t)(wid*32 + nj*16 + lr)*256 + ks*32 + 8*lg;
      bf16x8 bq_ = *(const bf16x8*)(wr_);
      bf16x8 bk_ = *(const bf16x8*)(wr_ + 65536);
      bf16x8 bv_ = *(const bf16x8*)(wr_ + 131072);
#pragma unroll
      for (int mi=0;mi<4;mi++){
        qa[mi][nj] = MFMA_BF16(af[mi], bq_, qa[mi][nj], 0,0,0);
        ka[mi][nj] = MFMA_BF16(af[mi], bk_, ka[mi][nj], 0,0,0);
        va[mi][nj] = MFMA_BF16(af[mi], bv_, va[mi][nj], 0,0,0);
      }
    }
  }

  // ---- Phase 3: q/k/v -> wave-private LDS ----
  u16* q_l = &lds[16384 + wid*7424];
  u16* k_l = q_l + 2560;
  u16* v_l = q_l + 5120;
  const float scale = 0.1767766952966369f; // 32^-0.5
#pragma unroll
  for (int mi=0;mi<4;mi++)
#pragma unroll
  for (int nj=0;nj<2;nj++){
    int dim = nj*16+lr;
    float bq_ = bqkv[wid*32+dim], bk_ = bqkv[256+wid*32+dim], bv_ = bqkv[512+wid*32+dim];
#pragma unroll
    for (int r=0;r<4;r++){
      int tok = mi*16+4*lg+r;
      q_l[tok*40+dim] = f2bf((qa[mi][nj][r]+bq_)*scale);
      k_l[tok*40+dim] = f2bf(ka[mi][nj][r]+bk_);
    }
    ushort4 vp;
    vp.x = f2bf(va[mi][nj][0]+bv_); vp.y = f2bf(va[mi][nj][1]+bv_);
    vp.z = f2bf(va[mi][nj][2]+bv_); vp.w = f2bf(va[mi][nj][3]+bv_);
    *(ushort4*)(&v_l[dim*72 + mi*16 + 4*lg]) = vp;
  }

  // ---- Phase 4: QK^T + bias/mask + softmax ----
  bf16x8 qf[4], kf[4];
#pragma unroll
  for (int i=0;i<4;i++){
    qf[i] = *(const bf16x8*)(&q_l[(i*16+lr)*40 + 8*lg]);
    kf[i] = *(const bf16x8*)(&k_l[(i*16+lr)*40 + 8*lg]);
  }
  f32x4 acc[4][4] = {};
#pragma unroll
  for (int mi=0;mi<4;mi++)
#pragma unroll
  for (int nj=0;nj<4;nj++)
    acc[mi][nj] = MFMA_BF16(qf[mi], kf[nj], acc[mi][nj], 0,0,0);

  int cls = ((wh==7) ? 2 : 0) | ((wwi==7) ? 1 : 0);
  const float* fbh = fb + (((size_t)cls*8 + wid) << 12);
#pragma unroll
  for (int mi=0;mi<4;mi++)
#pragma unroll
  for (int r=0;r<4;r++){
    int m = mi*16 + 4*lg + r;
#pragma unroll
    for (int nj=0;nj<4;nj++)
      acc[mi][nj][r] += fbh[m*64 + nj*16 + lr];
  }
#pragma unroll
  for (int mi=0;mi<4;mi++)
#pragma unroll
  for (int r=0;r<4;r++){
    float mx = fmaxf(fmaxf(acc[mi][0][r], acc[mi][1][r]), fmaxf(acc[mi][2][r], acc[mi][3][r]));
    for (int off=1; off<16; off<<=1) mx = fmaxf(mx, __shfl_xor(mx, off));
    float s = 0.f;
#pragma unroll
    for (int nj=0;nj<4;nj++){ float e = __expf(acc[mi][nj][r]-mx); acc[mi][nj][r]=e; s+=e; }
    for (int off=1; off<16; off<<=1) s += __shfl_xor(s, off);
    float inv = 1.f/s;
#pragma unroll
    for (int nj=0;nj<4;nj++) acc[mi][nj][r] *= inv;
  }

  // P overwrites q_l/k_l: fence so no qf/kf ds_read is still outstanding and
  // the compiler cannot reorder the P ds_writes above them (rule 18).
  asm volatile("s_waitcnt lgkmcnt(0)" ::: "memory");
  __builtin_amdgcn_sched_barrier(0);

  u16* P_l = q_l;   // [64][72]
#pragma unroll
  for (int mi=0;mi<4;mi++)
#pragma unroll
  for (int nj=0;nj<4;nj++)
#pragma unroll
  for (int r=0;r<4;r++)
    P_l[(mi*16+4*lg+r)*72 + nj*16 + lr] = f2bf(acc[mi][nj][r]);

  // ---- Phase 5: PV + store ----
  f32x4 acc2[4][2] = {};
#pragma unroll
  for (int ks=0; ks<2; ks++){
    bf16x8 vf0 = *(const bf16x8*)(&v_l[(lr)*72 + ks*32 + 8*lg]);
    bf16x8 vf1 = *(const bf16x8*)(&v_l[(16+lr)*72 + ks*32 + 8*lg]);
#pragma unroll
    for (int mi=0;mi<4;mi++){
      bf16x8 pf = *(const bf16x8*)(&P_l[(mi*16+lr)*72 + ks*32 + 8*lg]);
      acc2[mi][0] = MFMA_BF16(pf, vf0, acc2[mi][0], 0,0,0);
      acc2[mi][1] = MFMA_BF16(pf, vf1, acc2[mi][1], 0,0,0);
    }
  }
#pragma unroll
  for (int mi=0;mi<4;mi++)
#pragma unroll
  for (int nt=0;nt<2;nt++)
#pragma unroll
  for (int r=0;r<4;r++)
    outp[((size_t)gw*64 + mi*16+4*lg+r)*256 + wid*32 + nt*16 + lr] = f2bf(acc2[mi][nt][r]);
}

// ============ 256x256-tile GEMM engine: A[M][K] @ Bt[N][K], fp32 acc ============
#define GSTAGE(buf, k0)                                                  \
  _Pragma("unroll")                                                      \
  for (int c = 0; c < 4; c++){                                           \
    int row = c*64 + srow;                                               \
    gll16(Aw + (size_t)row*K + (k0) + (scb>>1), &As[buf][c*4096 + tid*8]); \
    gll16(Bw + (size_t)row*K + (k0) + (scb>>1), &Bs[buf][c*4096 + tid*8]); \
  }

// EPI 2: +b1, exact GELU, bf16 row-major out [m][1024]
// EPI 3: +b2, +hs residual (fp32), fp32 out
template<int EPI, bool SWZ>
__global__ __launch_bounds__(512, 2) void k_gemm256(const u16* __restrict__ A, const u16* __restrict__ Bt,
                                                    const float* __restrict__ bias, const float* __restrict__ res,
                                                    void* __restrict__ outp, int K){
  __shared__ __align__(16) u16 As[2][16384];
  __shared__ __align__(16) u16 Bs[2][16384];
  int tid = threadIdx.x, lane = tid & 63, wid = tid >> 6;
  int g = lane >> 4, lr = lane & 15;
  int wr = wid >> 2, wc = wid & 3;
  int bx, by;
  if constexpr (SWZ){
    int nwg = gridDim.x*gridDim.y;
    int bid = blockIdx.y*gridDim.x + blockIdx.x;
    int cpx = nwg >> 3;
    int swz = (bid & 7)*cpx + (bid >> 3);
    bx = swz % gridDim.x; by = swz / gridDim.x;
  } else { bx = blockIdx.x; by = blockIdx.y; }
  int m0 = by*256, n0 = bx*256;
  const u16* Aw = A + (size_t)m0*K;
  const u16* Bw = Bt + (size_t)n0*K;
  int srow = tid >> 3;
  int scb  = ((tid & 7)*16) ^ ((srow & 7) << 4);
  f32x4 acc[8][4] = {};
  int nt = K >> 6;

  GSTAGE(0, 0)
  for (int t = 0; t < nt; t++){
    __syncthreads();
    if (t+1 < nt){ GSTAGE((t+1)&1, (t+1)<<6) }
    int b = t & 1;
#pragma unroll
    for (int kk = 0; kk < 2; kk++){
      int cbr = (kk*64 + 16*g) ^ ((lr & 7) << 4);
      bf16x8 af[8], bf[4];
#pragma unroll
      for (int i=0;i<8;i++)
        af[i] = *(const bf16x8*)(&As[b][(wr*128 + i*16 + lr)*64 + (cbr>>1)]);
#pragma unroll
      for (int j=0;j<4;j++)
        bf[j] = *(const bf16x8*)(&Bs[b][(wc*64 + j*16 + lr)*64 + (cbr>>1)]);
#pragma unroll
      for (int mi=0;mi<8;mi++)
#pragma unroll
      for (int nj=0;nj<4;nj++)
        acc[mi][nj] = MFMA_BF16(af[mi], bf[nj], acc[mi][nj], 0,0,0);
    }
  }

#pragma unroll
  for (int mi=0; mi<8; mi++)
#pragma unroll
  for (int nj=0; nj<4; nj++){
    int n = n0 + wc*64 + nj*16 + lr;
#pragma unroll
    for (int r=0; r<4; r++){
      int m = m0 + wr*128 + mi*16 + 4*g + r;
      float val = acc[mi][nj][r] + bias[n];
      if constexpr (EPI==2){
        float gv = 0.5f*val*(1.f + erff(val*0.70710678118654752f));
        ((u16*)outp)[(size_t)m*1024 + n] = f2bf(gv);
      } else {
        ((float*)outp)[(size_t)m*256 + n] = val + res[(size_t)m*256 + n];
      }
    }
  }
}

// ------- O-proj 256x256 (BN=256 = full row) + window reverse + residual + fused LN2 -------
__global__ __launch_bounds__(512, 2) void k_oproj(const u16* __restrict__ A, const u16* __restrict__ Bt,
                                                  const float* __restrict__ bo, const float* __restrict__ hidden,
                                                  const float* __restrict__ g2, const float* __restrict__ b2v,
                                                  float* __restrict__ hs_out, u16* __restrict__ y2){
  __shared__ __align__(16) u16 As[2][16384];
  __shared__ __align__(16) u16 Bs[2][16384];
  __shared__ float part_s[256][4];
  __shared__ float part_q[256][4];
  const int K = 256;
  int tid = threadIdx.x, lane = tid & 63, wid = tid >> 6;
  int g = lane >> 4, lr = lane & 15;
  int wr = wid >> 2, wc = wid & 3;
  int m0 = blockIdx.x*256;
  const u16* Aw = A + (size_t)m0*K;
  const u16* Bw = Bt;
  int srow = tid >> 3;
  int scb  = ((tid & 7)*16) ^ ((srow & 7) << 4);
  f32x4 acc[8][4] = {};
  int nt = 4;

  GSTAGE(0, 0)
  for (int t = 0; t < nt; t++){
    __syncthreads();
    if (t+1 < nt){ GSTAGE((t+1)&1, (t+1)<<6) }
    int b = t & 1;
#pragma unroll
    for (int kk = 0; kk < 2; kk++){
      int cbr = (kk*64 + 16*g) ^ ((lr & 7) << 4);
      bf16x8 af[8], bf[4];
#pragma unroll
      for (int i=0;i<8;i++)
        af[i] = *(const bf16x8*)(&As[b][(wr*128 + i*16 + lr)*64 + (cbr>>1)]);
#pragma unroll
      for (int j=0;j<4;j++)
        bf[j] = *(const bf16x8*)(&Bs[b][(wc*64 + j*16 + lr)*64 + (cbr>>1)]);
#pragma unroll
      for (int mi=0;mi<8;mi++)
#pragma unroll
      for (int nj=0;nj<4;nj++)
        acc[mi][nj] = MFMA_BF16(af[mi], bf[nj], acc[mi][nj], 0,0,0);
    }
  }

  float bov[4], g2v[4], b2vv[4];
#pragma unroll
  for (int nj=0;nj<4;nj++){
    int n = wc*64 + nj*16 + lr;
    bov[nj] = bo[n]; g2v[nj] = g2[n]; b2vv[nj] = b2v[n];
  }
#pragma unroll
  for (int mi=0;mi<8;mi++)
#pragma unroll
  for (int r=0;r<4;r++){
    int rowl = wr*128 + mi*16 + 4*g + r;
    int m = m0 + rowl;
    int bi = m >> 12, win = (m >> 6) & 63, p = m & 63;
    int hh = ((win >> 3)*8 + (p >> 3) + 4) & 63;
    int ww = ((win & 7)*8 + (p & 7) + 4) & 63;
    size_t base = ((size_t)bi*4096 + hh*64 + ww)*256;
    float s = 0.f, sq = 0.f;
#pragma unroll
    for (int nj=0;nj<4;nj++){
      int n = wc*64 + nj*16 + lr;
      float val = acc[mi][nj][r] + bov[nj] + hidden[base + n];
      hs_out[base + n] = val;
      acc[mi][nj][r] = val;
      s += val; sq += val*val;
    }
    for (int off=1; off<16; off<<=1){ s += __shfl_xor(s, off); sq += __shfl_xor(sq, off); }
    if (lr == 0){ part_s[rowl][wc] = s; part_q[rowl][wc] = sq; }
  }
  __syncthreads();
#pragma unroll
  for (int mi=0;mi<8;mi++)
#pragma unroll
  for (int r=0;r<4;r++){
    int rowl = wr*128 + mi*16 + 4*g + r;
    int m = m0 + rowl;
    int bi = m >> 12, win = (m >> 6) & 63, p = m & 63;
    int hh = ((win >> 3)*8 + (p >> 3) + 4) & 63;
    int ww = ((win & 7)*8 + (p & 7) + 4) & 63;
    size_t base = ((size_t)bi*4096 + hh*64 + ww)*256;
    float sum = part_s[rowl][0] + part_s[rowl][1] + part_s[rowl][2] + part_s[rowl][3];
    float sqq = part_q[rowl][0] + part_q[rowl][1] + part_q[rowl][2] + part_q[rowl][3];
    float mean = sum*(1.f/256.f);
    float inv = rsqrtf(sqq*(1.f/256.f) - mean*mean + 1e-5f);
#pragma unroll
    for (int nj=0;nj<4;nj++){
      int n = wc*64 + nj*16 + lr;
      y2[base + n] = f2bf((acc[mi][nj][r]-mean)*inv*g2v[nj] + b2vv[nj]);
    }
  }
}

extern "C" void kernel_launch(void* const* d_in, const int* in_sizes, int n_in,
                              void* d_out, int out_size, void* d_ws, size_t ws_size,
                              hipStream_t stream){
  const float* hidden = (const float*)d_in[0];
  const float* ln1g = (const float*)d_in[1];
  const float* ln1b = (const float*)d_in[2];
  const float* wq   = (const float*)d_in[3];
  const float* bq   = (const float*)d_in[4];
  const float* wk   = (const float*)d_in[5];
  const float* bk   = (const float*)d_in[6];
  const float* wv   = (const float*)d_in[7];
  const float* bv   = (const float*)d_in[8];
  const float* btab = (const float*)d_in[9];
  const float* wo   = (const float*)d_in[10];
  const float* bo   = (const float*)d_in[11];
  const float* ln2g = (const float*)d_in[12];
  const float* ln2b = (const float*)d_in[13];
  const float* w1   = (const float*)d_in[14];
  const float* b1   = (const float*)d_in[15];
  const float* w2   = (const float*)d_in[16];
  const float* b2   = (const float*)d_in[17];
  float* out = (float*)d_out;

  char* ws = (char*)d_ws;
  const size_t MB = 1ull << 20;
  u16* xw    = (u16*)ws;                 // [0,64M): attn out
  u16* y1c   = (u16*)(ws + 64*MB);       // [64M,192M): FC1 chunk out
  u16* y2ln  = (u16*)(ws + 192*MB);      // [192M,256M): LN2 out
  u16* wqkvT = (u16*)(ws + 256*MB);      // bf16 weights, transposed [N][K]
  u16* woT   = wqkvT + 768*256;
  u16* w1T   = woT + 256*256;
  u16* w2T   = w1T + 1024*256;
  float* bqkv = (float*)(w2T + 1024*256);
  float* fbias = bqkv + 1024;            // 4*8*64*64 fp32 = 512KB

  // weight prep
  k_transpose<<<256, 256, 0, stream>>>(wq, wqkvT,          256, 256);
  k_transpose<<<256, 256, 0, stream>>>(wk, wqkvT + 65536,  256, 256);
  k_transpose<<<256, 256, 0, stream>>>(wv, wqkvT + 131072, 256, 256);
  k_transpose<<<256, 256, 0, stream>>>(wo, woT,            256, 256);
  k_transpose<<<1024,256, 0, stream>>>(w1, w1T,            256, 1024);
  k_transpose<<<1024,256, 0, stream>>>(w2, w2T,            1024, 256);
  k_concat_bias<<<1, 768, 0, stream>>>(bq, bk, bv, bqkv);
  k_bias<<<512, 256, 0, stream>>>(btab, fbias);

  // fused LN1 + shift + QKV + attention -> xw
  k_fattn<<<2048, 512, 0, stream>>>(hidden, ln1g, ln1b, wqkvT, bqkv, fbias, xw);
  // O-proj + window reverse + residual -> hs (d_out), fused LN2 -> y2ln
  k_oproj<<<512, 512, 0, stream>>>(xw, woT, bo, hidden, ln2g, ln2b, out, y2ln);
  // MLP in 2 M-chunks of 65536 rows
  for (int mc = 0; mc < 2; mc++){
    k_gemm256<2,true><<<dim3(4, 256), 512, 0, stream>>>(y2ln + (size_t)mc*65536*256, w1T, b1, nullptr, y1c, 256);
    k_gemm256<3,false><<<dim3(1, 256), 512, 0, stream>>>(y1c, w2T, b2,
                                                         out + (size_t)mc*65536*256,
                                                         out + (size_t)mc*65536*256, 1024);
  }
}

// Round 7
// 618.271 us; speedup vs baseline: 1.2811x; 1.0888x over previous
//
#include <hip/hip_runtime.h>
#include <hip/hip_bf16.h>
#include <math.h>

typedef unsigned short u16;
typedef __attribute__((ext_vector_type(8))) short bf16x8;
typedef __attribute__((ext_vector_type(8))) unsigned short u16x8;
typedef __attribute__((ext_vector_type(4))) float f32x4;

#define MFMA_BF16 __builtin_amdgcn_mfma_f32_16x16x32_bf16

__device__ __forceinline__ u16 f2bf(float f){
  union { float f; unsigned u; } v; v.f = f;
  unsigned r = v.u + 0x7FFFu + ((v.u >> 16) & 1u);
  return (u16)(r >> 16);
}

__device__ __forceinline__ void gll16(const void* g, void* l){
  __builtin_amdgcn_global_load_lds(
      (const __attribute__((address_space(1))) unsigned int*)g,
      (__attribute__((address_space(3))) unsigned int*)l, 16, 0, 0);
}

// ---------------- weight prep: fp32 [K][N] -> bf16 [N][K] ----------------
__global__ void k_transpose(const float* __restrict__ src, u16* __restrict__ dst, int K, int N){
  int idx = blockIdx.x*256 + threadIdx.x;
  if (idx >= K*N) return;
  int n = idx / K, k = idx - n*K;
  dst[idx] = f2bf(src[(size_t)k*N + n]);
}

__global__ void k_concat_bias(const float* __restrict__ a, const float* __restrict__ b,
                              const float* __restrict__ c, float* __restrict__ o){
  int i = threadIdx.x;  // 768 threads
  o[i] = i < 256 ? a[i] : (i < 512 ? b[i-256] : c[i-512]);
}

// ---- QKV weights in MFMA-fragment-major order ----
// fragW[type][h][ks][nj][lane][j] = W_type[k = ks*32 + 8*(lane>>4) + j][n = h*32 + nj*16 + (lane&15)]
__global__ __launch_bounds__(256) void k_fragw(const float* __restrict__ wq, const float* __restrict__ wk,
                                               const float* __restrict__ wv, u16* __restrict__ fragW){
  int idx = blockIdx.x*256 + threadIdx.x;    // 3*65536
  int j = idx & 7, lane = (idx >> 3) & 63, nj = (idx >> 9) & 1;
  int ks = (idx >> 10) & 7, h = (idx >> 13) & 7, type = idx >> 16;
  const float* w = type == 0 ? wq : (type == 1 ? wk : wv);
  int k = ks*32 + 8*(lane >> 4) + j;
  int n = h*32 + nj*16 + (lane & 15);
  fragW[idx] = f2bf(w[(size_t)k*256 + n]);
}

// ---- fused rel-pos bias + shift mask, fragment layout: fb2[cls][h][m][lr][nj] ----
// value at (row m, col n = nj*16+lr)
__global__ __launch_bounds__(256) void k_bias(const float* __restrict__ btab, float* __restrict__ fb){
  int idx = blockIdx.x*256 + threadIdx.x;   // 4*8*64*64 = 131072
  int nj = idx & 3, lr = (idx >> 2) & 15, m = (idx >> 6) & 63, hh = (idx >> 12) & 7, cls = idx >> 15;
  int n = nj*16 + lr;
  int r1=m>>3, c1=m&7, r2=n>>3, c2=n&7;
  float bv = btab[((r1-r2+7)*15 + (c1-c2+7))*8 + hh];
  int whe = cls>>1, wwe = cls&1;
  int a1 = (whe ? (r1<4?1:2) : 0)*3 + (wwe ? (c1<4?1:2) : 0);
  int a2 = (whe ? (r2<4?1:2) : 0)*3 + (wwe ? (c2<4?1:2) : 0);
  fb[idx] = bv + ((a1!=a2) ? -100.f : 0.f);
}

// ======== FUSED LN1 + QKV-projection + windowed attention ========
// One block per window (2048). 8 waves = 8 heads. q/k/v never touch HBM.
// LDS (u16): xb[64][256] swizzled at [0,16384); per-wave base 16384 + wid*7432:
//   q[64][40], k[64][40], vT[32][72]; P[64][72] aliases q+k; out tile aliases q.
__global__ __launch_bounds__(512) void k_fattn(const float* __restrict__ hidden,
    const float* __restrict__ g1, const float* __restrict__ b1f,
    const u16* __restrict__ fragW, const float* __restrict__ bqkv,
    const float* __restrict__ fb, u16* __restrict__ outp)
{
  __shared__ __align__(16) u16 lds[75840];   // 151680 B
  int tid = threadIdx.x, lane = tid & 63, wid = tid >> 6;
  int lg = lane >> 4, lr = lane & 15;
  int gw = blockIdx.x;
  int bi = gw >> 6, win = gw & 63, wh = win >> 3, wwi = win & 7;

  // ---- Phase 1: LN1 + cyclic-shift gather -> xb (chunk-XOR swizzled) ----
  {
    int t = wid*8 + (lane >> 3);           // token 0..63
    int j = lane & 7;                      // 32-channel chunk
    int hh_ = (wh*8 + (t >> 3) + 4) & 63;
    int ww_ = (wwi*8 + (t & 7) + 4) & 63;
    const float4* row = (const float4*)(hidden + ((size_t)bi*4096 + hh_*64 + ww_)*256) + j*8;
    float4 v[8]; float s = 0.f, sq = 0.f;
#pragma unroll
    for (int i=0;i<8;i++){
      v[i] = row[i];
      s  += v[i].x+v[i].y+v[i].z+v[i].w;
      sq += v[i].x*v[i].x+v[i].y*v[i].y+v[i].z*v[i].z+v[i].w*v[i].w;
    }
    s += __shfl_xor(s,1); sq += __shfl_xor(sq,1);
    s += __shfl_xor(s,2); sq += __shfl_xor(sq,2);
    s += __shfl_xor(s,4); sq += __shfl_xor(sq,4);
    float mean = s*(1.f/256.f);
    float inv = rsqrtf(sq*(1.f/256.f) - mean*mean + 1e-5f);
    const float4* gg = (const float4*)g1 + j*8;
    const float4* bb = (const float4*)b1f + j*8;
#pragma unroll
    for (int i2=0;i2<4;i2++){
      float4 a0=v[2*i2], a1=v[2*i2+1];
      float4 g0=gg[2*i2], g1_=gg[2*i2+1];
      float4 b0=bb[2*i2], b1_=bb[2*i2+1];
      u16x8 pk;
      pk[0]=f2bf((a0.x-mean)*inv*g0.x+b0.x); pk[1]=f2bf((a0.y-mean)*inv*g0.y+b0.y);
      pk[2]=f2bf((a0.z-mean)*inv*g0.z+b0.z); pk[3]=f2bf((a0.w-mean)*inv*g0.w+b0.w);
      pk[4]=f2bf((a1.x-mean)*inv*g1_.x+b1_.x); pk[5]=f2bf((a1.y-mean)*inv*g1_.y+b1_.y);
      pk[6]=f2bf((a1.z-mean)*inv*g1_.z+b1_.z); pk[7]=f2bf((a1.w-mean)*inv*g1_.w+b1_.w);
      int c = (j*4+i2) ^ (t & 7);
      *(u16x8*)(&lds[t*256 + c*8]) = pk;
    }
  }
  __syncthreads();

  // ---- Phase 2: mini-GEMM q/k/v for head `wid` (coalesced fragW from L2) ----
  f32x4 qa[4][2]={}, ka[4][2]={}, va[4][2]={};
#pragma unroll
  for (int ks=0; ks<8; ks++){
    bf16x8 af[4];
#pragma unroll
    for (int mi=0;mi<4;mi++){
      int tok = mi*16+lr;
      af[mi] = *(const bf16x8*)(&lds[tok*256 + (((ks*4+lg) ^ (tok&7))*8)]);
    }
    const u16* fq = fragW + ((((size_t)wid)*8 + ks)*2)*512 + lane*8;
#pragma unroll
    for (int nj=0;nj<2;nj++){
      bf16x8 bq_ = *(const bf16x8*)(fq + nj*512);
      bf16x8 bk_ = *(const bf16x8*)(fq + 65536 + nj*512);
      bf16x8 bv_ = *(const bf16x8*)(fq + 131072 + nj*512);
#pragma unroll
      for (int mi=0;mi<4;mi++){
        qa[mi][nj] = MFMA_BF16(af[mi], bq_, qa[mi][nj], 0,0,0);
        ka[mi][nj] = MFMA_BF16(af[mi], bk_, ka[mi][nj], 0,0,0);
        va[mi][nj] = MFMA_BF16(af[mi], bv_, va[mi][nj], 0,0,0);
      }
    }
  }

  // ---- Phase 3: q/k/v -> wave-private LDS ----
  u16* q_l = &lds[16384 + wid*7432];
  u16* k_l = q_l + 2560;
  u16* v_l = q_l + 5120;
  const float scale = 0.1767766952966369f; // 32^-0.5
#pragma unroll
  for (int mi=0;mi<4;mi++)
#pragma unroll
  for (int nj=0;nj<2;nj++){
    int dim = nj*16+lr;
    float bq_ = bqkv[wid*32+dim], bk_ = bqkv[256+wid*32+dim], bv_ = bqkv[512+wid*32+dim];
#pragma unroll
    for (int r=0;r<4;r++){
      int tok = mi*16+4*lg+r;
      q_l[tok*40+dim] = f2bf((qa[mi][nj][r]+bq_)*scale);
      k_l[tok*40+dim] = f2bf(ka[mi][nj][r]+bk_);
    }
    ushort4 vp;
    vp.x = f2bf(va[mi][nj][0]+bv_); vp.y = f2bf(va[mi][nj][1]+bv_);
    vp.z = f2bf(va[mi][nj][2]+bv_); vp.w = f2bf(va[mi][nj][3]+bv_);
    *(ushort4*)(&v_l[dim*72 + mi*16 + 4*lg]) = vp;
  }

  // ---- Phase 4: QK^T + bias/mask + softmax ----
  bf16x8 qf[4], kf[4];
#pragma unroll
  for (int i=0;i<4;i++){
    qf[i] = *(const bf16x8*)(&q_l[(i*16+lr)*40 + 8*lg]);
    kf[i] = *(const bf16x8*)(&k_l[(i*16+lr)*40 + 8*lg]);
  }
  f32x4 acc[4][4] = {};
#pragma unroll
  for (int mi=0;mi<4;mi++)
#pragma unroll
  for (int nj=0;nj<4;nj++)
    acc[mi][nj] = MFMA_BF16(qf[mi], kf[nj], acc[mi][nj], 0,0,0);

  int cls = ((wh==7) ? 2 : 0) | ((wwi==7) ? 1 : 0);
  const float4* fb4 = (const float4*)(fb + (((size_t)cls*8 + wid) << 12));
#pragma unroll
  for (int mi=0;mi<4;mi++)
#pragma unroll
  for (int r=0;r<4;r++){
    int m = mi*16 + 4*lg + r;
    float4 bv4 = fb4[m*16 + lr];
#pragma unroll
    for (int nj=0;nj<4;nj++)
      acc[mi][nj][r] += bv4[nj];
  }
#pragma unroll
  for (int mi=0;mi<4;mi++)
#pragma unroll
  for (int r=0;r<4;r++){
    float mx = fmaxf(fmaxf(acc[mi][0][r], acc[mi][1][r]), fmaxf(acc[mi][2][r], acc[mi][3][r]));
    for (int off=1; off<16; off<<=1) mx = fmaxf(mx, __shfl_xor(mx, off));
    float s = 0.f;
#pragma unroll
    for (int nj=0;nj<4;nj++){ float e = __expf(acc[mi][nj][r]-mx); acc[mi][nj][r]=e; s+=e; }
    for (int off=1; off<16; off<<=1) s += __shfl_xor(s, off);
    float inv = 1.f/s;
#pragma unroll
    for (int nj=0;nj<4;nj++) acc[mi][nj][r] *= inv;
  }

  // P overwrites q_l/k_l: fence (rule 18)
  asm volatile("s_waitcnt lgkmcnt(0)" ::: "memory");
  __builtin_amdgcn_sched_barrier(0);

  u16* P_l = q_l;   // [64][72]
#pragma unroll
  for (int mi=0;mi<4;mi++)
#pragma unroll
  for (int nj=0;nj<4;nj++)
#pragma unroll
  for (int r=0;r<4;r++)
    P_l[(mi*16+4*lg+r)*72 + nj*16 + lr] = f2bf(acc[mi][nj][r]);

  // ---- Phase 5: PV ----
  f32x4 acc2[4][2] = {};
#pragma unroll
  for (int ks=0; ks<2; ks++){
    bf16x8 vf0 = *(const bf16x8*)(&v_l[(lr)*72 + ks*32 + 8*lg]);
    bf16x8 vf1 = *(const bf16x8*)(&v_l[(16+lr)*72 + ks*32 + 8*lg]);
#pragma unroll
    for (int mi=0;mi<4;mi++){
      bf16x8 pf = *(const bf16x8*)(&P_l[(mi*16+lr)*72 + ks*32 + 8*lg]);
      acc2[mi][0] = MFMA_BF16(pf, vf0, acc2[mi][0], 0,0,0);
      acc2[mi][1] = MFMA_BF16(pf, vf1, acc2[mi][1], 0,0,0);
    }
  }

  // ---- Phase 6: out tile -> dead q region, then block-cooperative coalesced store ----
  asm volatile("s_waitcnt lgkmcnt(0)" ::: "memory");   // P/v reads done before overwrite
  __builtin_amdgcn_sched_barrier(0);
#pragma unroll
  for (int mi=0;mi<4;mi++)
#pragma unroll
  for (int nt=0;nt<2;nt++)
#pragma unroll
  for (int r=0;r<4;r++)
    q_l[(mi*16+4*lg+r)*32 + nt*16 + lr] = f2bf(acc2[mi][nt][r]);
  __syncthreads();
#pragma unroll
  for (int p=0;p<4;p++){
    int linear = p*4096 + tid*8;        // u16 index within 64x256 out tile
    int tok = linear >> 8, ch = linear & 255;
    int ws_ = ch >> 5, d = ch & 31;
    u16x8 val = *(const u16x8*)(&lds[16384 + ws_*7432 + tok*32 + d]);
    *(u16x8*)(&outp[((size_t)gw*64 + tok)*256 + ch]) = val;
  }
}

// ============ 256x256-tile GEMM engine: A[M][K] @ Bt[N][K], fp32 acc ============
#define GSTAGE(buf, k0)                                                  \
  _Pragma("unroll")                                                      \
  for (int c = 0; c < 4; c++){                                           \
    int row = c*64 + srow;                                               \
    gll16(Aw + (size_t)row*K + (k0) + (scb>>1), &As[buf][c*4096 + tid*8]); \
    gll16(Bw + (size_t)row*K + (k0) + (scb>>1), &Bs[buf][c*4096 + tid*8]); \
  }

// EPI 2: +b1, exact GELU, bf16 row-major out [m][1024]
// EPI 3: +b2, +hs residual (fp32), fp32 out
template<int EPI, bool SWZ>
__global__ __launch_bounds__(512, 2) void k_gemm256(const u16* __restrict__ A, const u16* __restrict__ Bt,
                                                    const float* __restrict__ bias, const float* __restrict__ res,
                                                    void* __restrict__ outp, int K){
  __shared__ __align__(16) u16 As[2][16384];
  __shared__ __align__(16) u16 Bs[2][16384];
  int tid = threadIdx.x, lane = tid & 63, wid = tid >> 6;
  int g = lane >> 4, lr = lane & 15;
  int wr = wid >> 2, wc = wid & 3;
  int bx, by;
  if constexpr (SWZ){
    int nwg = gridDim.x*gridDim.y;
    int bid = blockIdx.y*gridDim.x + blockIdx.x;
    int cpx = nwg >> 3;
    int swz = (bid & 7)*cpx + (bid >> 3);
    bx = swz % gridDim.x; by = swz / gridDim.x;
  } else { bx = blockIdx.x; by = blockIdx.y; }
  int m0 = by*256, n0 = bx*256;
  const u16* Aw = A + (size_t)m0*K;
  const u16* Bw = Bt + (size_t)n0*K;
  int srow = tid >> 3;
  int scb  = ((tid & 7)*16) ^ ((srow & 7) << 4);
  f32x4 acc[8][4] = {};
  int nt = K >> 6;

  GSTAGE(0, 0)
  for (int t = 0; t < nt; t++){
    __syncthreads();
    if (t+1 < nt){ GSTAGE((t+1)&1, (t+1)<<6) }
    int b = t & 1;
#pragma unroll
    for (int kk = 0; kk < 2; kk++){
      int cbr = (kk*64 + 16*g) ^ ((lr & 7) << 4);
      bf16x8 af[8], bf[4];
#pragma unroll
      for (int i=0;i<8;i++)
        af[i] = *(const bf16x8*)(&As[b][(wr*128 + i*16 + lr)*64 + (cbr>>1)]);
#pragma unroll
      for (int j=0;j<4;j++)
        bf[j] = *(const bf16x8*)(&Bs[b][(wc*64 + j*16 + lr)*64 + (cbr>>1)]);
#pragma unroll
      for (int mi=0;mi<8;mi++)
#pragma unroll
      for (int nj=0;nj<4;nj++)
        acc[mi][nj] = MFMA_BF16(af[mi], bf[nj], acc[mi][nj], 0,0,0);
    }
  }

#pragma unroll
  for (int mi=0; mi<8; mi++)
#pragma unroll
  for (int nj=0; nj<4; nj++){
    int n = n0 + wc*64 + nj*16 + lr;
#pragma unroll
    for (int r=0; r<4; r++){
      int m = m0 + wr*128 + mi*16 + 4*g + r;
      float val = acc[mi][nj][r] + bias[n];
      if constexpr (EPI==2){
        float gv = 0.5f*val*(1.f + erff(val*0.70710678118654752f));
        ((u16*)outp)[(size_t)m*1024 + n] = f2bf(gv);
      } else {
        ((float*)outp)[(size_t)m*256 + n] = val + res[(size_t)m*256 + n];
      }
    }
  }
}

// ------- O-proj 256x256 (BN=256 = full row) + window reverse + residual + fused LN2 -------
__global__ __launch_bounds__(512, 2) void k_oproj(const u16* __restrict__ A, const u16* __restrict__ Bt,
                                                  const float* __restrict__ bo, const float* __restrict__ hidden,
                                                  const float* __restrict__ g2, const float* __restrict__ b2v,
                                                  float* __restrict__ hs_out, u16* __restrict__ y2){
  __shared__ __align__(16) u16 As[2][16384];
  __shared__ __align__(16) u16 Bs[2][16384];
  __shared__ float part_s[256][4];
  __shared__ float part_q[256][4];
  const int K = 256;
  int tid = threadIdx.x, lane = tid & 63, wid = tid >> 6;
  int g = lane >> 4, lr = lane & 15;
  int wr = wid >> 2, wc = wid & 3;
  int m0 = blockIdx.x*256;
  const u16* Aw = A + (size_t)m0*K;
  const u16* Bw = Bt;
  int srow = tid >> 3;
  int scb  = ((tid & 7)*16) ^ ((srow & 7) << 4);
  f32x4 acc[8][4] = {};
  int nt = 4;

  GSTAGE(0, 0)
  for (int t = 0; t < nt; t++){
    __syncthreads();
    if (t+1 < nt){ GSTAGE((t+1)&1, (t+1)<<6) }
    int b = t & 1;
#pragma unroll
    for (int kk = 0; kk < 2; kk++){
      int cbr = (kk*64 + 16*g) ^ ((lr & 7) << 4);
      bf16x8 af[8], bf[4];
#pragma unroll
      for (int i=0;i<8;i++)
        af[i] = *(const bf16x8*)(&As[b][(wr*128 + i*16 + lr)*64 + (cbr>>1)]);
#pragma unroll
      for (int j=0;j<4;j++)
        bf[j] = *(const bf16x8*)(&Bs[b][(wc*64 + j*16 + lr)*64 + (cbr>>1)]);
#pragma unroll
      for (int mi=0;mi<8;mi++)
#pragma unroll
      for (int nj=0;nj<4;nj++)
        acc[mi][nj] = MFMA_BF16(af[mi], bf[nj], acc[mi][nj], 0,0,0);
    }
  }

  float bov[4], g2v[4], b2vv[4];
#pragma unroll
  for (int nj=0;nj<4;nj++){
    int n = wc*64 + nj*16 + lr;
    bov[nj] = bo[n]; g2v[nj] = g2[n]; b2vv[nj] = b2v[n];
  }
#pragma unroll
  for (int mi=0;mi<8;mi++)
#pragma unroll
  for (int r=0;r<4;r++){
    int rowl = wr*128 + mi*16 + 4*g + r;
    int m = m0 + rowl;
    int bi = m >> 12, win = (m >> 6) & 63, p = m & 63;
    int hh = ((win >> 3)*8 + (p >> 3) + 4) & 63;
    int ww = ((win & 7)*8 + (p & 7) + 4) & 63;
    size_t base = ((size_t)bi*4096 + hh*64 + ww)*256;
    float s = 0.f, sq = 0.f;
#pragma unroll
    for (int nj=0;nj<4;nj++){
      int n = wc*64 + nj*16 + lr;
      float val = acc[mi][nj][r] + bov[nj] + hidden[base + n];
      hs_out[base + n] = val;
      acc[mi][nj][r] = val;
      s += val; sq += val*val;
    }
    for (int off=1; off<16; off<<=1){ s += __shfl_xor(s, off); sq += __shfl_xor(sq, off); }
    if (lr == 0){ part_s[rowl][wc] = s; part_q[rowl][wc] = sq; }
  }
  __syncthreads();
#pragma unroll
  for (int mi=0;mi<8;mi++)
#pragma unroll
  for (int r=0;r<4;r++){
    int rowl = wr*128 + mi*16 + 4*g + r;
    int m = m0 + rowl;
    int bi = m >> 12, win = (m >> 6) & 63, p = m & 63;
    int hh = ((win >> 3)*8 + (p >> 3) + 4) & 63;
    int ww = ((win & 7)*8 + (p & 7) + 4) & 63;
    size_t base = ((size_t)bi*4096 + hh*64 + ww)*256;
    float sum = part_s[rowl][0] + part_s[rowl][1] + part_s[rowl][2] + part_s[rowl][3];
    float sqq = part_q[rowl][0] + part_q[rowl][1] + part_q[rowl][2] + part_q[rowl][3];
    float mean = sum*(1.f/256.f);
    float inv = rsqrtf(sqq*(1.f/256.f) - mean*mean + 1e-5f);
#pragma unroll
    for (int nj=0;nj<4;nj++){
      int n = wc*64 + nj*16 + lr;
      y2[base + n] = f2bf((acc[mi][nj][r]-mean)*inv*g2v[nj] + b2vv[nj]);
    }
  }
}

extern "C" void kernel_launch(void* const* d_in, const int* in_sizes, int n_in,
                              void* d_out, int out_size, void* d_ws, size_t ws_size,
                              hipStream_t stream){
  const float* hidden = (const float*)d_in[0];
  const float* ln1g = (const float*)d_in[1];
  const float* ln1b = (const float*)d_in[2];
  const float* wq   = (const float*)d_in[3];
  const float* bq   = (const float*)d_in[4];
  const float* wk   = (const float*)d_in[5];
  const float* bk   = (const float*)d_in[6];
  const float* wv   = (const float*)d_in[7];
  const float* bv   = (const float*)d_in[8];
  const float* btab = (const float*)d_in[9];
  const float* wo   = (const float*)d_in[10];
  const float* bo   = (const float*)d_in[11];
  const float* ln2g = (const float*)d_in[12];
  const float* ln2b = (const float*)d_in[13];
  const float* w1   = (const float*)d_in[14];
  const float* b1   = (const float*)d_in[15];
  const float* w2   = (const float*)d_in[16];
  const float* b2   = (const float*)d_in[17];
  float* out = (float*)d_out;

  char* ws = (char*)d_ws;
  const size_t MB = 1ull << 20;
  u16* xw    = (u16*)ws;                 // [0,64M): attn out
  u16* y1c   = (u16*)(ws + 64*MB);       // [64M,192M): FC1 chunk out
  u16* y2ln  = (u16*)(ws + 192*MB);      // [192M,256M): LN2 out
  u16* fragW = (u16*)(ws + 256*MB);      // QKV weights, fragment-major (384KB)
  u16* woT   = fragW + 196608;
  u16* w1T   = woT + 256*256;
  u16* w2T   = w1T + 1024*256;
  float* bqkv = (float*)(w2T + 1024*256);
  float* fbias = bqkv + 1024;            // 4*8*64*64 fp32 = 512KB

  // weight prep
  k_fragw<<<768, 256, 0, stream>>>(wq, wk, wv, fragW);
  k_transpose<<<256, 256, 0, stream>>>(wo, woT,  256, 256);
  k_transpose<<<1024,256, 0, stream>>>(w1, w1T,  256, 1024);
  k_transpose<<<1024,256, 0, stream>>>(w2, w2T,  1024, 256);
  k_concat_bias<<<1, 768, 0, stream>>>(bq, bk, bv, bqkv);
  k_bias<<<512, 256, 0, stream>>>(btab, fbias);

  // fused LN1 + shift + QKV + attention -> xw
  k_fattn<<<2048, 512, 0, stream>>>(hidden, ln1g, ln1b, fragW, bqkv, fbias, xw);
  // O-proj + window reverse + residual -> hs (d_out), fused LN2 -> y2ln
  k_oproj<<<512, 512, 0, stream>>>(xw, woT, bo, hidden, ln2g, ln2b, out, y2ln);
  // MLP in 2 M-chunks of 65536 rows
  for (int mc = 0; mc < 2; mc++){
    k_gemm256<2,true><<<dim3(4, 256), 512, 0, stream>>>(y2ln + (size_t)mc*65536*256, w1T, b1, nullptr, y1c, 256);
    k_gemm256<3,false><<<dim3(1, 256), 512, 0, stream>>>(y1c, w2T, b2,
                                                         out + (size_t)mc*65536*256,
                                                         out + (size_t)mc*65536*256, 1024);
  }
}

// Round 8
// 609.611 us; speedup vs baseline: 1.2993x; 1.0142x over previous
//
#include <hip/hip_runtime.h>
#include <hip/hip_bf16.h>
#include <math.h>

typedef unsigned short u16;
typedef __attribute__((ext_vector_type(8))) short bf16x8;
typedef __attribute__((ext_vector_type(8))) unsigned short u16x8;
typedef __attribute__((ext_vector_type(4))) float f32x4;

#define MFMA_BF16 __builtin_amdgcn_mfma_f32_16x16x32_bf16

__device__ __forceinline__ u16 f2bf(float f){
  union { float f; unsigned u; } v; v.f = f;
  unsigned r = v.u + 0x7FFFu + ((v.u >> 16) & 1u);
  return (u16)(r >> 16);
}

__device__ __forceinline__ void gll16(const void* g, void* l){
  __builtin_amdgcn_global_load_lds(
      (const __attribute__((address_space(1))) unsigned int*)g,
      (__attribute__((address_space(3))) unsigned int*)l, 16, 0, 0);
}

// ---------------- weight prep: fp32 [K][N] -> bf16 [N][K] ----------------
__global__ void k_transpose(const float* __restrict__ src, u16* __restrict__ dst, int K, int N){
  int idx = blockIdx.x*256 + threadIdx.x;
  if (idx >= K*N) return;
  int n = idx / K, k = idx - n*K;
  dst[idx] = f2bf(src[(size_t)k*N + n]);
}

__global__ void k_concat_bias(const float* __restrict__ a, const float* __restrict__ b,
                              const float* __restrict__ c, float* __restrict__ o){
  int i = threadIdx.x;  // 768 threads
  o[i] = i < 256 ? a[i] : (i < 512 ? b[i-256] : c[i-512]);
}

// ---- QKV weights in MFMA-fragment-major order ----
// fragW[type][h][ks][nj][lane][j] = W_type[k = ks*32 + 8*(lane>>4) + j][n = h*32 + nj*16 + (lane&15)]
__global__ __launch_bounds__(256) void k_fragw(const float* __restrict__ wq, const float* __restrict__ wk,
                                               const float* __restrict__ wv, u16* __restrict__ fragW){
  int idx = blockIdx.x*256 + threadIdx.x;    // 3*65536
  int j = idx & 7, lane = (idx >> 3) & 63, nj = (idx >> 9) & 1;
  int ks = (idx >> 10) & 7, h = (idx >> 13) & 7, type = idx >> 16;
  const float* w = type == 0 ? wq : (type == 1 ? wk : wv);
  int k = ks*32 + 8*(lane >> 4) + j;
  int n = h*32 + nj*16 + (lane & 15);
  fragW[idx] = f2bf(w[(size_t)k*256 + n]);
}

// ---- fused rel-pos bias + shift mask, fragment layout: fb2[cls][h][m][lr][nj] ----
__global__ __launch_bounds__(256) void k_bias(const float* __restrict__ btab, float* __restrict__ fb){
  int idx = blockIdx.x*256 + threadIdx.x;   // 4*8*64*64 = 131072
  int nj = idx & 3, lr = (idx >> 2) & 15, m = (idx >> 6) & 63, hh = (idx >> 12) & 7, cls = idx >> 15;
  int n = nj*16 + lr;
  int r1=m>>3, c1=m&7, r2=n>>3, c2=n&7;
  float bv = btab[((r1-r2+7)*15 + (c1-c2+7))*8 + hh];
  int whe = cls>>1, wwe = cls&1;
  int a1 = (whe ? (r1<4?1:2) : 0)*3 + (wwe ? (c1<4?1:2) : 0);
  int a2 = (whe ? (r2<4?1:2) : 0)*3 + (wwe ? (c2<4?1:2) : 0);
  fb[idx] = bv + ((a1!=a2) ? -100.f : 0.f);
}

// ======== FUSED LN1 + QKV-projection + windowed attention ========
// One block per window (2048). 8 waves = 8 heads. q/k/v never touch HBM.
__global__ __launch_bounds__(512) void k_fattn(const float* __restrict__ hidden,
    const float* __restrict__ g1, const float* __restrict__ b1f,
    const u16* __restrict__ fragW, const float* __restrict__ bqkv,
    const float* __restrict__ fb, u16* __restrict__ outp)
{
  __shared__ __align__(16) u16 lds[75840];   // 151680 B
  int tid = threadIdx.x, lane = tid & 63, wid = tid >> 6;
  int lg = lane >> 4, lr = lane & 15;
  int gw = blockIdx.x;
  int bi = gw >> 6, win = gw & 63, wh = win >> 3, wwi = win & 7;

  // ---- Phase 1: LN1 + cyclic-shift gather -> xb (chunk-XOR swizzled) ----
  {
    int t = wid*8 + (lane >> 3);           // token 0..63
    int j = lane & 7;                      // 32-channel chunk
    int hh_ = (wh*8 + (t >> 3) + 4) & 63;
    int ww_ = (wwi*8 + (t & 7) + 4) & 63;
    const float4* row = (const float4*)(hidden + ((size_t)bi*4096 + hh_*64 + ww_)*256) + j*8;
    float4 v[8]; float s = 0.f, sq = 0.f;
#pragma unroll
    for (int i=0;i<8;i++){
      v[i] = row[i];
      s  += v[i].x+v[i].y+v[i].z+v[i].w;
      sq += v[i].x*v[i].x+v[i].y*v[i].y+v[i].z*v[i].z+v[i].w*v[i].w;
    }
    s += __shfl_xor(s,1); sq += __shfl_xor(sq,1);
    s += __shfl_xor(s,2); sq += __shfl_xor(sq,2);
    s += __shfl_xor(s,4); sq += __shfl_xor(sq,4);
    float mean = s*(1.f/256.f);
    float inv = rsqrtf(sq*(1.f/256.f) - mean*mean + 1e-5f);
    const float4* gg = (const float4*)g1 + j*8;
    const float4* bb = (const float4*)b1f + j*8;
#pragma unroll
    for (int i2=0;i2<4;i2++){
      float4 a0=v[2*i2], a1=v[2*i2+1];
      float4 g0=gg[2*i2], g1_=gg[2*i2+1];
      float4 b0=bb[2*i2], b1_=bb[2*i2+1];
      u16x8 pk;
      pk[0]=f2bf((a0.x-mean)*inv*g0.x+b0.x); pk[1]=f2bf((a0.y-mean)*inv*g0.y+b0.y);
      pk[2]=f2bf((a0.z-mean)*inv*g0.z+b0.z); pk[3]=f2bf((a0.w-mean)*inv*g0.w+b0.w);
      pk[4]=f2bf((a1.x-mean)*inv*g1_.x+b1_.x); pk[5]=f2bf((a1.y-mean)*inv*g1_.y+b1_.y);
      pk[6]=f2bf((a1.z-mean)*inv*g1_.z+b1_.z); pk[7]=f2bf((a1.w-mean)*inv*g1_.w+b1_.w);
      int c = (j*4+i2) ^ (t & 7);
      *(u16x8*)(&lds[t*256 + c*8]) = pk;
    }
  }
  __syncthreads();

  // ---- Phase 2: mini-GEMM q/k/v for head `wid` (coalesced fragW from L2) ----
  f32x4 qa[4][2]={}, ka[4][2]={}, va[4][2]={};
  __builtin_amdgcn_s_setprio(1);
#pragma unroll
  for (int ks=0; ks<8; ks++){
    bf16x8 af[4];
#pragma unroll
    for (int mi=0;mi<4;mi++){
      int tok = mi*16+lr;
      af[mi] = *(const bf16x8*)(&lds[tok*256 + (((ks*4+lg) ^ (tok&7))*8)]);
    }
    const u16* fq = fragW + ((((size_t)wid)*8 + ks)*2)*512 + lane*8;
#pragma unroll
    for (int nj=0;nj<2;nj++){
      bf16x8 bq_ = *(const bf16x8*)(fq + nj*512);
      bf16x8 bk_ = *(const bf16x8*)(fq + 65536 + nj*512);
      bf16x8 bv_ = *(const bf16x8*)(fq + 131072 + nj*512);
#pragma unroll
      for (int mi=0;mi<4;mi++){
        qa[mi][nj] = MFMA_BF16(af[mi], bq_, qa[mi][nj], 0,0,0);
        ka[mi][nj] = MFMA_BF16(af[mi], bk_, ka[mi][nj], 0,0,0);
        va[mi][nj] = MFMA_BF16(af[mi], bv_, va[mi][nj], 0,0,0);
      }
    }
  }
  __builtin_amdgcn_s_setprio(0);

  // ---- Phase 3: q/k/v -> wave-private LDS ----
  u16* q_l = &lds[16384 + wid*7432];
  u16* k_l = q_l + 2560;
  u16* v_l = q_l + 5120;
  const float scale = 0.1767766952966369f; // 32^-0.5
#pragma unroll
  for (int mi=0;mi<4;mi++)
#pragma unroll
  for (int nj=0;nj<2;nj++){
    int dim = nj*16+lr;
    float bq_ = bqkv[wid*32+dim], bk_ = bqkv[256+wid*32+dim], bv_ = bqkv[512+wid*32+dim];
#pragma unroll
    for (int r=0;r<4;r++){
      int tok = mi*16+4*lg+r;
      q_l[tok*40+dim] = f2bf((qa[mi][nj][r]+bq_)*scale);
      k_l[tok*40+dim] = f2bf(ka[mi][nj][r]+bk_);
    }
    ushort4 vp;
    vp.x = f2bf(va[mi][nj][0]+bv_); vp.y = f2bf(va[mi][nj][1]+bv_);
    vp.z = f2bf(va[mi][nj][2]+bv_); vp.w = f2bf(va[mi][nj][3]+bv_);
    *(ushort4*)(&v_l[dim*72 + mi*16 + 4*lg]) = vp;
  }

  // ---- Phase 4: QK^T + bias/mask + softmax ----
  bf16x8 qf[4], kf[4];
#pragma unroll
  for (int i=0;i<4;i++){
    qf[i] = *(const bf16x8*)(&q_l[(i*16+lr)*40 + 8*lg]);
    kf[i] = *(const bf16x8*)(&k_l[(i*16+lr)*40 + 8*lg]);
  }
  f32x4 acc[4][4] = {};
#pragma unroll
  for (int mi=0;mi<4;mi++)
#pragma unroll
  for (int nj=0;nj<4;nj++)
    acc[mi][nj] = MFMA_BF16(qf[mi], kf[nj], acc[mi][nj], 0,0,0);

  int cls = ((wh==7) ? 2 : 0) | ((wwi==7) ? 1 : 0);
  const float4* fb4 = (const float4*)(fb + (((size_t)cls*8 + wid) << 12));
#pragma unroll
  for (int mi=0;mi<4;mi++)
#pragma unroll
  for (int r=0;r<4;r++){
    int m = mi*16 + 4*lg + r;
    float4 bv4 = fb4[m*16 + lr];
#pragma unroll
    for (int nj=0;nj<4;nj++)
      acc[mi][nj][r] += bv4[nj];
  }
#pragma unroll
  for (int mi=0;mi<4;mi++)
#pragma unroll
  for (int r=0;r<4;r++){
    float mx = fmaxf(fmaxf(acc[mi][0][r], acc[mi][1][r]), fmaxf(acc[mi][2][r], acc[mi][3][r]));
    for (int off=1; off<16; off<<=1) mx = fmaxf(mx, __shfl_xor(mx, off));
    float s = 0.f;
#pragma unroll
    for (int nj=0;nj<4;nj++){ float e = __expf(acc[mi][nj][r]-mx); acc[mi][nj][r]=e; s+=e; }
    for (int off=1; off<16; off<<=1) s += __shfl_xor(s, off);
    float inv = 1.f/s;
#pragma unroll
    for (int nj=0;nj<4;nj++) acc[mi][nj][r] *= inv;
  }

  // P overwrites q_l/k_l: fence (rule 18)
  asm volatile("s_waitcnt lgkmcnt(0)" ::: "memory");
  __builtin_amdgcn_sched_barrier(0);

  u16* P_l = q_l;   // [64][72]
#pragma unroll
  for (int mi=0;mi<4;mi++)
#pragma unroll
  for (int nj=0;nj<4;nj++)
#pragma unroll
  for (int r=0;r<4;r++)
    P_l[(mi*16+4*lg+r)*72 + nj*16 + lr] = f2bf(acc[mi][nj][r]);

  // ---- Phase 5: PV ----
  f32x4 acc2[4][2] = {};
#pragma unroll
  for (int ks=0; ks<2; ks++){
    bf16x8 vf0 = *(const bf16x8*)(&v_l[(lr)*72 + ks*32 + 8*lg]);
    bf16x8 vf1 = *(const bf16x8*)(&v_l[(16+lr)*72 + ks*32 + 8*lg]);
#pragma unroll
    for (int mi=0;mi<4;mi++){
      bf16x8 pf = *(const bf16x8*)(&P_l[(mi*16+lr)*72 + ks*32 + 8*lg]);
      acc2[mi][0] = MFMA_BF16(pf, vf0, acc2[mi][0], 0,0,0);
      acc2[mi][1] = MFMA_BF16(pf, vf1, acc2[mi][1], 0,0,0);
    }
  }

  // ---- Phase 6: out tile -> wave-private LDS [64][32], then vectorized store ----
  asm volatile("s_waitcnt lgkmcnt(0)" ::: "memory");   // P/v reads done before overwrite
  __builtin_amdgcn_sched_barrier(0);
#pragma unroll
  for (int mi=0;mi<4;mi++)
#pragma unroll
  for (int nt=0;nt<2;nt++)
#pragma unroll
  for (int r=0;r<4;r++)
    q_l[(mi*16+4*lg+r)*32 + nt*16 + lr] = f2bf(acc2[mi][nt][r]);
  asm volatile("s_waitcnt lgkmcnt(0)" ::: "memory");
  __builtin_amdgcn_sched_barrier(0);
#pragma unroll
  for (int p=0;p<4;p++){
    int linear = p*512 + lane*8;        // u16 index within this wave's 64x32 tile
    int tok = linear >> 5, d = linear & 31;
    u16x8 val = *(const u16x8*)(&q_l[linear]);
    *(u16x8*)(&outp[((size_t)gw*64 + tok)*256 + wid*32 + d]) = val;
  }
}

// ============ 256x256-tile GEMM engine: A[M][K] @ Bt[N][K], fp32 acc ============
// 8 waves (2M x 4N), BK=64, dbuf, XOR-swizzled LDS, COUNTED-vmcnt pipeline:
// raw s_barrier + s_waitcnt vmcnt(8) -- next tile's 8 loads stay in flight
// across the barriers (T3/T4: never drain vmcnt to 0 in the main loop).
#define GSTAGE(buf, k0)                                                  \
  _Pragma("unroll")                                                      \
  for (int c = 0; c < 4; c++){                                           \
    int row = c*64 + srow;                                               \
    gll16(Aw + (size_t)row*K + (k0) + (scb>>1), &As[buf][c*4096 + tid*8]); \
    gll16(Bw + (size_t)row*K + (k0) + (scb>>1), &Bs[buf][c*4096 + tid*8]); \
  }

#define GLOOP_BODY(b)                                                    \
  _Pragma("unroll")                                                      \
  for (int kk = 0; kk < 2; kk++){                                        \
    int cbr = (kk*64 + 16*g) ^ ((lr & 7) << 4);                          \
    bf16x8 af[8], bf[4];                                                 \
    _Pragma("unroll")                                                    \
    for (int i=0;i<8;i++)                                                \
      af[i] = *(const bf16x8*)(&As[b][(wr*128 + i*16 + lr)*64 + (cbr>>1)]); \
    _Pragma("unroll")                                                    \
    for (int j=0;j<4;j++)                                                \
      bf[j] = *(const bf16x8*)(&Bs[b][(wc*64 + j*16 + lr)*64 + (cbr>>1)]); \
    _Pragma("unroll")                                                    \
    for (int mi=0;mi<8;mi++)                                             \
    _Pragma("unroll")                                                    \
    for (int nj=0;nj<4;nj++)                                             \
      acc[mi][nj] = MFMA_BF16(af[mi], bf[nj], acc[mi][nj], 0,0,0);       \
  }

#define GLOOP(nt)                                                        \
  GSTAGE(0, 0)                                                           \
  GSTAGE(1, 64)                                                          \
  for (int t = 0; t < (nt); t++){                                        \
    if (t+1 < (nt)) asm volatile("s_waitcnt vmcnt(8)" ::: "memory");     \
    else            asm volatile("s_waitcnt vmcnt(0)" ::: "memory");     \
    __builtin_amdgcn_s_barrier();                                        \
    __builtin_amdgcn_sched_barrier(0);                                   \
    int b = t & 1;                                                       \
    GLOOP_BODY(b)                                                        \
    __builtin_amdgcn_sched_barrier(0);                                   \
    asm volatile("s_waitcnt lgkmcnt(0)" ::: "memory");                   \
    __builtin_amdgcn_s_barrier();                                        \
    __builtin_amdgcn_sched_barrier(0);                                   \
    if (t+2 < (nt)){ GSTAGE(b, (t+2)<<6) }                               \
  }

// EPI 2: +b1, exact GELU, bf16 row-major out [m][1024]
// EPI 3: +b2, +hs residual (fp32), fp32 out
template<int EPI, bool SWZ>
__global__ __launch_bounds__(512, 2) void k_gemm256(const u16* __restrict__ A, const u16* __restrict__ Bt,
                                                    const float* __restrict__ bias, const float* __restrict__ res,
                                                    void* __restrict__ outp, int K){
  __shared__ __align__(16) u16 As[2][16384];
  __shared__ __align__(16) u16 Bs[2][16384];
  int tid = threadIdx.x, lane = tid & 63, wid = tid >> 6;
  int g = lane >> 4, lr = lane & 15;
  int wr = wid >> 2, wc = wid & 3;
  int bx, by;
  if constexpr (SWZ){
    int nwg = gridDim.x*gridDim.y;
    int bid = blockIdx.y*gridDim.x + blockIdx.x;
    int cpx = nwg >> 3;
    int swz = (bid & 7)*cpx + (bid >> 3);
    bx = swz % gridDim.x; by = swz / gridDim.x;
  } else { bx = blockIdx.x; by = blockIdx.y; }
  int m0 = by*256, n0 = bx*256;
  const u16* Aw = A + (size_t)m0*K;
  const u16* Bw = Bt + (size_t)n0*K;
  int srow = tid >> 3;
  int scb  = ((tid & 7)*16) ^ ((srow & 7) << 4);
  f32x4 acc[8][4] = {};
  int nt = K >> 6;

  GLOOP(nt)

#pragma unroll
  for (int mi=0; mi<8; mi++)
#pragma unroll
  for (int nj=0; nj<4; nj++){
    int n = n0 + wc*64 + nj*16 + lr;
#pragma unroll
    for (int r=0; r<4; r++){
      int m = m0 + wr*128 + mi*16 + 4*g + r;
      float val = acc[mi][nj][r] + bias[n];
      if constexpr (EPI==2){
        float gv = 0.5f*val*(1.f + erff(val*0.70710678118654752f));
        ((u16*)outp)[(size_t)m*1024 + n] = f2bf(gv);
      } else {
        ((float*)outp)[(size_t)m*256 + n] = val + res[(size_t)m*256 + n];
      }
    }
  }
}

// ------- O-proj 256x256 (BN=256 = full row) + window reverse + residual + fused LN2 -------
__global__ __launch_bounds__(512, 2) void k_oproj(const u16* __restrict__ A, const u16* __restrict__ Bt,
                                                  const float* __restrict__ bo, const float* __restrict__ hidden,
                                                  const float* __restrict__ g2, const float* __restrict__ b2v,
                                                  float* __restrict__ hs_out, u16* __restrict__ y2){
  __shared__ __align__(16) u16 As[2][16384];
  __shared__ __align__(16) u16 Bs[2][16384];
  __shared__ float part_s[256][4];
  __shared__ float part_q[256][4];
  const int K = 256;
  int tid = threadIdx.x, lane = tid & 63, wid = tid >> 6;
  int g = lane >> 4, lr = lane & 15;
  int wr = wid >> 2, wc = wid & 3;
  int m0 = blockIdx.x*256;
  const u16* Aw = A + (size_t)m0*K;
  const u16* Bw = Bt;
  int srow = tid >> 3;
  int scb  = ((tid & 7)*16) ^ ((srow & 7) << 4);
  f32x4 acc[8][4] = {};

  GLOOP(4)

  float bov[4], g2v[4], b2vv[4];
#pragma unroll
  for (int nj=0;nj<4;nj++){
    int n = wc*64 + nj*16 + lr;
    bov[nj] = bo[n]; g2v[nj] = g2[n]; b2vv[nj] = b2v[n];
  }
#pragma unroll
  for (int mi=0;mi<8;mi++)
#pragma unroll
  for (int r=0;r<4;r++){
    int rowl = wr*128 + mi*16 + 4*g + r;
    int m = m0 + rowl;
    int bi = m >> 12, win = (m >> 6) & 63, p = m & 63;
    int hh = ((win >> 3)*8 + (p >> 3) + 4) & 63;
    int ww = ((win & 7)*8 + (p & 7) + 4) & 63;
    size_t base = ((size_t)bi*4096 + hh*64 + ww)*256;
    float s = 0.f, sq = 0.f;
#pragma unroll
    for (int nj=0;nj<4;nj++){
      int n = wc*64 + nj*16 + lr;
      float val = acc[mi][nj][r] + bov[nj] + hidden[base + n];
      hs_out[base + n] = val;
      acc[mi][nj][r] = val;
      s += val; sq += val*val;
    }
    for (int off=1; off<16; off<<=1){ s += __shfl_xor(s, off); sq += __shfl_xor(sq, off); }
    if (lr == 0){ part_s[rowl][wc] = s; part_q[rowl][wc] = sq; }
  }
  __syncthreads();
#pragma unroll
  for (int mi=0;mi<8;mi++)
#pragma unroll
  for (int r=0;r<4;r++){
    int rowl = wr*128 + mi*16 + 4*g + r;
    int m = m0 + rowl;
    int bi = m >> 12, win = (m >> 6) & 63, p = m & 63;
    int hh = ((win >> 3)*8 + (p >> 3) + 4) & 63;
    int ww = ((win & 7)*8 + (p & 7) + 4) & 63;
    size_t base = ((size_t)bi*4096 + hh*64 + ww)*256;
    float sum = part_s[rowl][0] + part_s[rowl][1] + part_s[rowl][2] + part_s[rowl][3];
    float sqq = part_q[rowl][0] + part_q[rowl][1] + part_q[rowl][2] + part_q[rowl][3];
    float mean = sum*(1.f/256.f);
    float inv = rsqrtf(sqq*(1.f/256.f) - mean*mean + 1e-5f);
#pragma unroll
    for (int nj=0;nj<4;nj++){
      int n = wc*64 + nj*16 + lr;
      y2[base + n] = f2bf((acc[mi][nj][r]-mean)*inv*g2v[nj] + b2vv[nj]);
    }
  }
}

extern "C" void kernel_launch(void* const* d_in, const int* in_sizes, int n_in,
                              void* d_out, int out_size, void* d_ws, size_t ws_size,
                              hipStream_t stream){
  const float* hidden = (const float*)d_in[0];
  const float* ln1g = (const float*)d_in[1];
  const float* ln1b = (const float*)d_in[2];
  const float* wq   = (const float*)d_in[3];
  const float* bq   = (const float*)d_in[4];
  const float* wk   = (const float*)d_in[5];
  const float* bk   = (const float*)d_in[6];
  const float* wv   = (const float*)d_in[7];
  const float* bv   = (const float*)d_in[8];
  const float* btab = (const float*)d_in[9];
  const float* wo   = (const float*)d_in[10];
  const float* bo   = (const float*)d_in[11];
  const float* ln2g = (const float*)d_in[12];
  const float* ln2b = (const float*)d_in[13];
  const float* w1   = (const float*)d_in[14];
  const float* b1   = (const float*)d_in[15];
  const float* w2   = (const float*)d_in[16];
  const float* b2   = (const float*)d_in[17];
  float* out = (float*)d_out;

  char* ws = (char*)d_ws;
  const size_t MB = 1ull << 20;
  u16* xw    = (u16*)ws;                 // [0,64M): attn out
  u16* y1c   = (u16*)(ws + 64*MB);       // [64M,192M): FC1 chunk out
  u16* y2ln  = (u16*)(ws + 192*MB);      // [192M,256M): LN2 out
  u16* fragW = (u16*)(ws + 256*MB);      // QKV weights, fragment-major (384KB)
  u16* woT   = fragW + 196608;
  u16* w1T   = woT + 256*256;
  u16* w2T   = w1T + 1024*256;
  float* bqkv = (float*)(w2T + 1024*256);
  float* fbias = bqkv + 1024;            // 4*8*64*64 fp32 = 512KB

  // weight prep
  k_fragw<<<768, 256, 0, stream>>>(wq, wk, wv, fragW);
  k_transpose<<<256, 256, 0, stream>>>(wo, woT,  256, 256);
  k_transpose<<<1024,256, 0, stream>>>(w1, w1T,  256, 1024);
  k_transpose<<<1024,256, 0, stream>>>(w2, w2T,  1024, 256);
  k_concat_bias<<<1, 768, 0, stream>>>(bq, bk, bv, bqkv);
  k_bias<<<512, 256, 0, stream>>>(btab, fbias);

  // fused LN1 + shift + QKV + attention -> xw
  k_fattn<<<2048, 512, 0, stream>>>(hidden, ln1g, ln1b, fragW, bqkv, fbias, xw);
  // O-proj + window reverse + residual -> hs (d_out), fused LN2 -> y2ln
  k_oproj<<<512, 512, 0, stream>>>(xw, woT, bo, hidden, ln2g, ln2b, out, y2ln);
  // MLP in 2 M-chunks of 65536 rows
  for (int mc = 0; mc < 2; mc++){
    k_gemm256<2,true><<<dim3(4, 256), 512, 0, stream>>>(y2ln + (size_t)mc*65536*256, w1T, b1, nullptr, y1c, 256);
    k_gemm256<3,false><<<dim3(1, 256), 512, 0, stream>>>(y1c, w2T, b2,
                                                         out + (size_t)mc*65536*256,
                                                         out + (size_t)mc*65536*256, 1024);
  }
}